// Round 1
// baseline (4585.394 us; speedup 1.0000x reference)
//
#include <hip/hip_runtime.h>
#include <math.h>

// Problem dims (fixed by reference): N=64, C=512, H=W=16 (HW=256)
#define NB  64
#define CCH 512
#define HW  256

// ---------------------------------------------------------------------------
// conv3x3 core: one block computes out[n, co0..co0+63, all 256 pixels].
// 256 threads: thread t -> cog = t>>6 (16-co group), pg = t&63 -> pixel row
// h = pg>>2, 4 pixels w4..w4+3 (w4 = (pg&3)*4). 64 fp32 accumulators/thread.
// LDS: x halo tile (8 ci planes, 18x18 zero-padded) + weight tile [64][8][12].
// ---------------------------------------------------------------------------
__device__ __forceinline__ void conv_core(const float* __restrict__ xin,
                                          const float* __restrict__ Wg,
                                          int n, int co0,
                                          float (&acc)[16][4],
                                          float (&xs)[8][18][18],
                                          float (&wsl)[64][8][12])
{
    const int t   = threadIdx.x;
    const int pg  = t & 63;
    const int cog = t >> 6;
    const int h   = pg >> 2;
    const int w4  = (pg & 3) * 4;

#pragma unroll
    for (int i = 0; i < 16; ++i)
#pragma unroll
        for (int j = 0; j < 4; ++j) acc[i][j] = 0.f;

    for (int ci0 = 0; ci0 < CCH; ci0 += 8) {
        __syncthreads();  // protect previous tile's readers
        // stage x: 8 planes of 18x18 (zero halo)
        for (int idx = t; idx < 8 * 324; idx += 256) {
            int ci_l = idx / 324, r = idx - ci_l * 324;
            int hh = r / 18, ww = r - hh * 18;
            int hg = hh - 1, wg = ww - 1;
            float v = 0.f;
            if (((unsigned)hg < 16u) && ((unsigned)wg < 16u))
                v = xin[(((size_t)n * CCH + ci0 + ci_l) << 8) + (hg << 4) + wg];
            xs[ci_l][hh][ww] = v;
        }
        // stage weights: 64 co x 8 ci x 9 taps (padded to 12 for b128 alignment)
        for (int idx = t; idx < 64 * 8 * 9; idx += 256) {
            int co = idx / 72, r = idx - co * 72;
            int ci_l = r / 9, j = r - ci_l * 9;
            wsl[co][ci_l][j] = Wg[((size_t)(co0 + co) * CCH + ci0 + ci_l) * 9 + j];
        }
        __syncthreads();

#pragma unroll 1
        for (int ci_l = 0; ci_l < 8; ++ci_l) {
            // 3x6 input patch covering this thread's 4 output pixels
            float xr[3][6];
#pragma unroll
            for (int r = 0; r < 3; ++r)
#pragma unroll
                for (int c = 0; c < 6; ++c)
                    xr[r][c] = xs[ci_l][h + r][w4 + c];

#pragma unroll
            for (int co = 0; co < 16; ++co) {
                const float4 w0 = *(const float4*)&wsl[cog * 16 + co][ci_l][0];
                const float4 w1 = *(const float4*)&wsl[cog * 16 + co][ci_l][4];
                const float  w8 = wsl[cog * 16 + co][ci_l][8];
#pragma unroll
                for (int p = 0; p < 4; ++p) {
                    float s = acc[co][p];
                    s = fmaf(xr[0][p + 0], w0.x, s);
                    s = fmaf(xr[0][p + 1], w0.y, s);
                    s = fmaf(xr[0][p + 2], w0.z, s);
                    s = fmaf(xr[1][p + 0], w0.w, s);
                    s = fmaf(xr[1][p + 1], w1.x, s);
                    s = fmaf(xr[1][p + 2], w1.y, s);
                    s = fmaf(xr[2][p + 0], w1.z, s);
                    s = fmaf(xr[2][p + 1], w1.w, s);
                    s = fmaf(xr[2][p + 2], w8,   s);
                    acc[co][p] = s;
                }
            }
        }
    }
}

// conv for Q,K,V: writes pixel-major layout outT[p][n][c] (contiguous 64x512 per pixel)
__global__ __launch_bounds__(256) void conv_qkv_kernel(
    const float* __restrict__ x,
    const float* __restrict__ Wq, const float* __restrict__ Wk, const float* __restrict__ Wv,
    float* __restrict__ qT, float* __restrict__ kT, float* __restrict__ vT)
{
    __shared__ float xs[8][18][18];
    __shared__ float wsl[64][8][12];
    const int cot = blockIdx.x, n = blockIdx.y, set = blockIdx.z;
    const float* Wg  = (set == 0) ? Wq : (set == 1) ? Wk : Wv;
    float*       oT  = (set == 0) ? qT : (set == 1) ? kT : vT;
    const int co0 = cot * 64;

    float acc[16][4];
    conv_core(x, Wg, n, co0, acc, xs, wsl);

    const int t = threadIdx.x;
    const int pg = t & 63, cog = t >> 6;
    const int h = pg >> 2, w4 = (pg & 3) * 4;
#pragma unroll
    for (int p = 0; p < 4; ++p) {
        int pix = (h << 4) + w4 + p;
        float* dst = oT + ((size_t)pix * NB + n) * CCH + co0 + cog * 16;
#pragma unroll
        for (int q4 = 0; q4 < 4; ++q4) {
            float4 vv = make_float4(acc[q4 * 4 + 0][p], acc[q4 * 4 + 1][p],
                                    acc[q4 * 4 + 2][p], acc[q4 * 4 + 3][p]);
            *(float4*)(dst + q4 * 4) = vv;
        }
    }
}

// final conv + residual: reads y (NCHW), writes out = x + conv(y,Wc) (NCHW)
__global__ __launch_bounds__(256) void conv_res_kernel(
    const float* __restrict__ y, const float* __restrict__ Wc,
    const float* __restrict__ x, float* __restrict__ out)
{
    __shared__ float xs[8][18][18];
    __shared__ float wsl[64][8][12];
    const int cot = blockIdx.x, n = blockIdx.y;
    const int co0 = cot * 64;

    float acc[16][4];
    conv_core(y, Wc, n, co0, acc, xs, wsl);

    const int t = threadIdx.x;
    const int pg = t & 63, cog = t >> 6;
    const int h = pg >> 2, w4 = (pg & 3) * 4;
#pragma unroll
    for (int co = 0; co < 16; ++co) {
        int gco = co0 + cog * 16 + co;
        size_t base = ((size_t)n * CCH + gco) * HW + (h << 4) + w4;
        float4 xv = *(const float4*)(x + base);
        float4 ov;
        ov.x = acc[co][0] + xv.x;
        ov.y = acc[co][1] + xv.y;
        ov.z = acc[co][2] + xv.z;
        ov.w = acc[co][3] + xv.w;
        *(float4*)(out + base) = ov;
    }
}

// ---------------------------------------------------------------------------
// attention: one block per pixel p. S = qK^T/sqrt(C) (64x64), softmax over m,
// virt = att @ V (64x512). All panels contiguous in [p][n][c] layout.
// ---------------------------------------------------------------------------
__global__ __launch_bounds__(256) void attn_kernel(
    const float* __restrict__ qT, const float* __restrict__ kT,
    const float* __restrict__ vT, float* __restrict__ virtT)
{
    const int p = blockIdx.x;
    const int t = threadIdx.x;
    __shared__ float smemA[2][64][68];  // qs, ks; later reused as vs[64][132]
    __shared__ float attb[64][68];
    const size_t pb = (size_t)p * (NB * CCH);

    const int ng = t >> 4, mg = t & 15;
    const int n0 = ng * 4, m0 = mg * 4;
    float acc[4][4];
#pragma unroll
    for (int i = 0; i < 4; ++i)
#pragma unroll
        for (int j = 0; j < 4; ++j) acc[i][j] = 0.f;

    for (int ct = 0; ct < 8; ++ct) {
        const int c0 = ct * 64;
        __syncthreads();
#pragma unroll
        for (int k = 0; k < 4; ++k) {
            int f = t + k * 256;
            int nn = f >> 4, cc4 = f & 15;
            float4 qv = *(const float4*)(qT + pb + (size_t)nn * CCH + c0 + cc4 * 4);
            float4 kv = *(const float4*)(kT + pb + (size_t)nn * CCH + c0 + cc4 * 4);
            *(float4*)&smemA[0][nn][cc4 * 4] = qv;
            *(float4*)&smemA[1][nn][cc4 * 4] = kv;
        }
        __syncthreads();
#pragma unroll 4
        for (int c4 = 0; c4 < 16; ++c4) {
            float4 q4[4], k4[4];
#pragma unroll
            for (int i = 0; i < 4; ++i) q4[i] = *(const float4*)&smemA[0][n0 + i][c4 * 4];
#pragma unroll
            for (int j = 0; j < 4; ++j) k4[j] = *(const float4*)&smemA[1][m0 + j][c4 * 4];
#pragma unroll
            for (int i = 0; i < 4; ++i)
#pragma unroll
                for (int j = 0; j < 4; ++j) {
                    acc[i][j] = fmaf(q4[i].x, k4[j].x, acc[i][j]);
                    acc[i][j] = fmaf(q4[i].y, k4[j].y, acc[i][j]);
                    acc[i][j] = fmaf(q4[i].z, k4[j].z, acc[i][j]);
                    acc[i][j] = fmaf(q4[i].w, k4[j].w, acc[i][j]);
                }
        }
    }

    // softmax over m (row n0+i lives on the 16 consecutive lanes ng*16..+15)
    const float SCALE = 0.0441941738241592f;  // 1/sqrt(512)
#pragma unroll
    for (int i = 0; i < 4; ++i) {
        float m = fmaxf(fmaxf(acc[i][0], acc[i][1]), fmaxf(acc[i][2], acc[i][3]));
#pragma unroll
        for (int mask = 1; mask < 16; mask <<= 1) m = fmaxf(m, __shfl_xor(m, mask, 16));
        float e[4]; float s = 0.f;
#pragma unroll
        for (int j = 0; j < 4; ++j) { e[j] = __expf((acc[i][j] - m) * SCALE); s += e[j]; }
#pragma unroll
        for (int mask = 1; mask < 16; mask <<= 1) s += __shfl_xor(s, mask, 16);
        float inv = 1.f / s;
#pragma unroll
        for (int j = 0; j < 4; ++j) attb[n0 + i][m0 + j] = e[j] * inv;
    }
    __syncthreads();

    // PV: virt[n][c] = sum_m att[n][m] * v[m][c], c tiled by 128
    float* vs = &smemA[0][0][0];  // vs[m*132 + c] (8448 floats, fits in smemA)
    const int ng2 = t >> 3, cg = t & 7;
    const int nn0 = ng2 * 2, cb = cg * 16;
    for (int ct4 = 0; ct4 < 4; ++ct4) {
        const int c0 = ct4 * 128;
#pragma unroll
        for (int k = 0; k < 8; ++k) {
            int f = t + k * 256;
            int m = f >> 5, cc4 = f & 31;
            *(float4*)&vs[m * 132 + cc4 * 4] =
                *(const float4*)(vT + pb + (size_t)m * CCH + c0 + cc4 * 4);
        }
        __syncthreads();
        float acc2[2][16];
#pragma unroll
        for (int i = 0; i < 2; ++i)
#pragma unroll
            for (int j = 0; j < 16; ++j) acc2[i][j] = 0.f;
#pragma unroll 4
        for (int m = 0; m < 64; ++m) {
            float a0 = attb[nn0][m], a1 = attb[nn0 + 1][m];
#pragma unroll
            for (int k4 = 0; k4 < 4; ++k4) {
                float4 v4 = *(const float4*)&vs[m * 132 + cb + k4 * 4];
                acc2[0][k4 * 4 + 0] = fmaf(a0, v4.x, acc2[0][k4 * 4 + 0]);
                acc2[0][k4 * 4 + 1] = fmaf(a0, v4.y, acc2[0][k4 * 4 + 1]);
                acc2[0][k4 * 4 + 2] = fmaf(a0, v4.z, acc2[0][k4 * 4 + 2]);
                acc2[0][k4 * 4 + 3] = fmaf(a0, v4.w, acc2[0][k4 * 4 + 3]);
                acc2[1][k4 * 4 + 0] = fmaf(a1, v4.x, acc2[1][k4 * 4 + 0]);
                acc2[1][k4 * 4 + 1] = fmaf(a1, v4.y, acc2[1][k4 * 4 + 1]);
                acc2[1][k4 * 4 + 2] = fmaf(a1, v4.z, acc2[1][k4 * 4 + 2]);
                acc2[1][k4 * 4 + 3] = fmaf(a1, v4.w, acc2[1][k4 * 4 + 3]);
            }
        }
#pragma unroll
        for (int i = 0; i < 2; ++i)
#pragma unroll
            for (int k4 = 0; k4 < 4; ++k4) {
                float4 ov = make_float4(acc2[i][k4 * 4 + 0], acc2[i][k4 * 4 + 1],
                                        acc2[i][k4 * 4 + 2], acc2[i][k4 * 4 + 3]);
                *(float4*)(virtT + pb + (size_t)(nn0 + i) * CCH + c0 + cb + k4 * 4) = ov;
            }
        __syncthreads();  // before restaging vs
    }
}

// ---------------------------------------------------------------------------
// GroupNorm(1,C) + affine + ReLU. Input virtT [p][n][c]; output y NCHW.
// One block per sample. Two passes; pass 2 transposes via 64x65 LDS tiles.
// ---------------------------------------------------------------------------
__global__ __launch_bounds__(256) void gn_kernel(
    const float* __restrict__ virtT, const float* __restrict__ gamma,
    const float* __restrict__ beta, float* __restrict__ y)
{
    const int n = blockIdx.x;
    const int t = threadIdx.x;
    float sum = 0.f, ss = 0.f;
    for (int idx = t; idx < HW * CCH; idx += 256) {
        int p = idx >> 9, c = idx & 511;
        float v = virtT[((size_t)p * NB + n) * CCH + c];
        sum += v; ss = fmaf(v, v, ss);
    }
#pragma unroll
    for (int off = 32; off > 0; off >>= 1) {
        sum += __shfl_down(sum, off);
        ss  += __shfl_down(ss, off);
    }
    __shared__ float rs[4], rss[4], stats[2];
    const int wid = t >> 6, lane = t & 63;
    if (lane == 0) { rs[wid] = sum; rss[wid] = ss; }
    __syncthreads();
    if (t == 0) {
        float S = rs[0] + rs[1] + rs[2] + rs[3];
        float SS = rss[0] + rss[1] + rss[2] + rss[3];
        float mu = S * (1.f / 131072.f);
        float var = SS * (1.f / 131072.f) - mu * mu;
        stats[0] = mu;
        stats[1] = rsqrtf(var + 1e-5f);
    }
    __syncthreads();
    const float mu = stats[0], rstd = stats[1];

    __shared__ float tile[64][65];
    for (int pt = 0; pt < 4; ++pt)
        for (int ctile = 0; ctile < 8; ++ctile) {
            const int p0 = pt * 64, c0 = ctile * 64;
            __syncthreads();
            {
                const int cc = t & 63, pr = t >> 6;
#pragma unroll
                for (int k = 0; k < 16; ++k) {
                    int pp = pr + k * 4;
                    float v = virtT[((size_t)(p0 + pp) * NB + n) * CCH + c0 + cc];
                    v = (v - mu) * rstd;
                    v = fmaf(v, gamma[c0 + cc], beta[c0 + cc]);
                    v = fmaxf(v, 0.f);
                    tile[pp][cc] = v;
                }
            }
            __syncthreads();
            {
                const int pp2 = t & 63, cr = t >> 6;
#pragma unroll
                for (int k = 0; k < 16; ++k) {
                    int cc2 = cr + k * 4;
                    y[((size_t)n * CCH + c0 + cc2) * HW + p0 + pp2] = tile[pp2][cc2];
                }
            }
        }
}

// ---------------------------------------------------------------------------
extern "C" void kernel_launch(void* const* d_in, const int* in_sizes, int n_in,
                              void* d_out, int out_size, void* d_ws, size_t ws_size,
                              hipStream_t stream)
{
    const float* x     = (const float*)d_in[0];
    const float* Wq    = (const float*)d_in[1];
    const float* Wk    = (const float*)d_in[2];
    const float* Wv    = (const float*)d_in[3];
    const float* Wc    = (const float*)d_in[4];
    const float* gamma = (const float*)d_in[5];
    const float* beta  = (const float*)d_in[6];
    float* out = (float*)d_out;

    // workspace: 3 x 33.5MB fp32 buffers (needs ws_size >= 100663296 bytes)
    float* wsf = (float*)d_ws;
    float* qT = wsf;                 // later reused as virtT
    float* kT = wsf + 8388608;       // later reused as y (NCHW, post-GN)
    float* vT = wsf + 16777216;
    float* virtT = qT;
    float* y = kT;

    conv_qkv_kernel<<<dim3(8, 64, 3), dim3(256), 0, stream>>>(x, Wq, Wk, Wv, qT, kT, vT);
    attn_kernel<<<dim3(256), dim3(256), 0, stream>>>(qT, kT, vT, virtT);
    gn_kernel<<<dim3(64), dim3(256), 0, stream>>>(virtT, gamma, beta, y);
    conv_res_kernel<<<dim3(8, 64), dim3(256), 0, stream>>>(y, Wc, x, out);
}

// Round 2
// 518.846 us; speedup vs baseline: 8.8377x; 8.8377x over previous
//
#include <hip/hip_runtime.h>
#include <math.h>

typedef unsigned short u16;
typedef unsigned int u32;
typedef short short8 __attribute__((ext_vector_type(8)));
typedef float f32x4 __attribute__((ext_vector_type(4)));

#define NB 64
#define CCH 512
#define HW 256

// ---- bf16 helpers (bit-level, RNE) ----
__device__ __forceinline__ u16 f2bf(float f) {
    union { float f; u32 u; } x; x.f = f;
    u32 r = x.u + 0x7fffu + ((x.u >> 16) & 1u);
    return (u16)(r >> 16);
}
__device__ __forceinline__ float bf2f(u16 b) {
    union { u32 u; float f; } x; x.u = ((u32)b) << 16;
    return x.f;
}
__device__ __forceinline__ void gload_lds16(const u16* g, u16* l) {
    __builtin_amdgcn_global_load_lds((const __attribute__((address_space(1))) u32*)g,
                                     (__attribute__((address_space(3))) u32*)l, 16, 0, 0);
}

// ---------------------------------------------------------------------------
// zero the padded-image border cells (68 cells/sample x 512 c)
// ---------------------------------------------------------------------------
__global__ __launch_bounds__(256) void zero_borders(u16* __restrict__ pad) {
    const int n = blockIdx.x, t = threadIdx.x;
    short8 z = (short8){0,0,0,0,0,0,0,0};
    for (int idx = t; idx < 68 * 64; idx += 256) {
        int cell = idx >> 6, ch = idx & 63;
        int hh, ww;
        if (cell < 18)      { hh = 0;          ww = cell; }
        else if (cell < 36) { hh = 17;         ww = cell - 18; }
        else if (cell < 52) { hh = cell - 35;  ww = 0; }
        else                { hh = cell - 51;  ww = 17; }
        *(short8*)(pad + ((size_t)((n * 18 + hh) * 18 + ww)) * 512 + ch * 8) = z;
    }
}

// ---------------------------------------------------------------------------
// NCHW fp32 -> padded pixel-major bf16 [n][18][18][512] (interior only)
// grid (ptile=4, ctile=8, n=64); 64x64 transpose tile through LDS
// ---------------------------------------------------------------------------
__global__ __launch_bounds__(256) void prep_x(const float* __restrict__ x, u16* __restrict__ pad) {
    __shared__ float tl[64][65];
    const int n = blockIdx.z, c0 = blockIdx.y * 64, p0 = blockIdx.x * 64;
    const int t = threadIdx.x;
    {
        const int cc = t >> 2, ps = (t & 3) * 16;
#pragma unroll
        for (int i = 0; i < 4; ++i) {
            float4 v4 = *(const float4*)(x + (((size_t)(n * 512 + c0 + cc)) << 8) + p0 + ps + i * 4);
            tl[cc][ps + i * 4 + 0] = v4.x;
            tl[cc][ps + i * 4 + 1] = v4.y;
            tl[cc][ps + i * 4 + 2] = v4.z;
            tl[cc][ps + i * 4 + 3] = v4.w;
        }
    }
    __syncthreads();
    {
        const int pp = t >> 2, cs = (t & 3) * 16;
        short8 o0, o1;
#pragma unroll
        for (int i = 0; i < 8; ++i) o0[i] = (short)f2bf(tl[cs + i][pp]);
#pragma unroll
        for (int i = 0; i < 8; ++i) o1[i] = (short)f2bf(tl[cs + 8 + i][pp]);
        const int p = p0 + pp, h = p >> 4, wcol = p & 15;
        u16* dst = pad + ((size_t)((n * 18 + h + 1) * 18 + wcol + 1)) * 512 + c0 + cs;
        *(short8*)(dst + 0) = o0;
        *(short8*)(dst + 8) = o1;
    }
}

// ---------------------------------------------------------------------------
// weights fp32 [co][ci][3][3] -> bf16 Wt[sel][tap][co][ci]
// grid (co=512, sel=4)
// ---------------------------------------------------------------------------
__global__ __launch_bounds__(256) void prep_w(
    const float* __restrict__ Wq, const float* __restrict__ Wk,
    const float* __restrict__ Wv, const float* __restrict__ Wc,
    u16* __restrict__ Wt)
{
    __shared__ float lw[4608];
    const int co = blockIdx.x, sel = blockIdx.y, t = threadIdx.x;
    const float* Ws = (sel == 0) ? Wq : (sel == 1) ? Wk : (sel == 2) ? Wv : Wc;
#pragma unroll
    for (int i = 0; i < 18; ++i) lw[t + i * 256] = Ws[(size_t)co * 4608 + t + i * 256];
    __syncthreads();
    for (int tap = 0; tap < 9; ++tap)
#pragma unroll
        for (int hh = 0; hh < 2; ++hh) {
            int ci = t + hh * 256;
            Wt[(((size_t)(sel * 9 + tap)) << 18) + (co << 9) + ci] = f2bf(lw[ci * 9 + tap]);
        }
}

// ---------------------------------------------------------------------------
// conv3x3 as 9-tap implicit GEMM, bf16 MFMA 16x16x32, 128x128 tile, BK=32.
// MODE 0: M=im-rows (p-major: r=p*64+n), N=co; out q/k/v bf16 [imrow][co].
//   grid (x=Ntile 4, y=Mtile 128, z=sel 3)
// MODE 1: M=co, N=im-rows (n-major: r=n*256+p); out NCHW fp32 + residual.
//   grid (x=Ntile 128, y=Mtile 4)
// ---------------------------------------------------------------------------
template<int MODE>
__global__ __launch_bounds__(256, 2) void conv_mfma(
    const u16* __restrict__ pad, const u16* __restrict__ Wt,
    u16* __restrict__ q, u16* __restrict__ k, u16* __restrict__ v,
    const float* __restrict__ xres, float* __restrict__ out)
{
    __shared__ short bufA[2][4096];   // IM tile [128 rows][32 k]
    __shared__ short bufB[2][4096];   // W  tile [128 rows][32 k]
    const int t = threadIdx.x;
    const int l = t & 63;
    const int w = t >> 6;
    const int wr = w >> 1, wc = w & 1;

    int imbase, cobase;
    const u16* Wsel;
    if constexpr (MODE == 0) {
        imbase = blockIdx.y * 128;
        cobase = blockIdx.x * 128;
        Wsel = Wt + (size_t)blockIdx.z * 2359296;   // 9*512*512
    } else {
        imbase = blockIdx.x * 128;
        cobase = blockIdx.y * 128;
        Wsel = Wt;
    }

    // staging per-lane offsets. Wave loads 16 rows x 64B per gload (1KB).
    // Physical chunk cp=l&3 at row r holds logical chunk cp ^ swz(r),
    // swz(r) = (r ^ (r>>2)) & 3.
    const int lr = l >> 2;
    const int cl = (l & 3) ^ ((l >> 2) & 3) ^ ((l >> 4) & 3);
    int imoff[2], woff[2];
#pragma unroll
    for (int i = 0; i < 2; ++i) {
        int r = w * 32 + i * 16 + lr;
        int imrow = imbase + r;
        int n, p;
        if constexpr (MODE == 0) { p = imrow >> 6; n = imrow & 63; }
        else                     { n = imrow >> 8; p = imrow & 255; }
        int h = p >> 4, wco = p & 15;
        imoff[i] = ((n * 18 + h) * 18 + wco) * 512 + cl * 8;
        woff[i]  = (cobase + r) * 512 + cl * 8;
    }

    // fragment read: row = base + (l&15), logical chunk c = l>>4,
    // physical chunk = c ^ swz(row); swz(row) depends only on l&15.
    const int sw = (l & 3) ^ ((l >> 2) & 3);
    const int fragoff = (l & 15) * 32 + (((l >> 4) ^ sw) & 3) * 8;

    f32x4 acc[4][4];
#pragma unroll
    for (int a = 0; a < 4; ++a)
#pragma unroll
        for (int b = 0; b < 4; ++b) acc[a][b] = (f32x4){0.f, 0.f, 0.f, 0.f};

    auto STAGE = [&](int s, int j, int k0) {
        const int shift = ((j / 3) * 18 + (j % 3)) * 512 + k0;   // uniform
        const size_t wjo = ((size_t)j << 18) + k0;
#pragma unroll
        for (int i = 0; i < 2; ++i) {
            gload_lds16(pad  + imoff[i] + shift, (u16*)&bufA[s][(w * 32 + i * 16) * 32]);
            gload_lds16(Wsel + woff[i]  + wjo,   (u16*)&bufB[s][(w * 32 + i * 16) * 32]);
        }
    };

    STAGE(0, 0, 0);
    __syncthreads();

    for (int kt = 0; kt < 144; ++kt) {
        const int cur = kt & 1;
        if (kt < 143) {
            const int kn = kt + 1;
            STAGE(cur ^ 1, kn >> 4, (kn & 15) * 32);
        }
        short8 fa[4], fb[4];
        const short* IMb = &bufA[cur][0];
        const short* Wb  = &bufB[cur][0];
#pragma unroll
        for (int f = 0; f < 4; ++f) {
            const int imr = ((MODE == 0) ? wr : wc) * 64 + f * 16;
            const int wrr = ((MODE == 0) ? wc : wr) * 64 + f * 16;
            short8 sim = *(const short8*)(IMb + imr * 32 + fragoff);
            short8 swt = *(const short8*)(Wb  + wrr * 32 + fragoff);
            if constexpr (MODE == 0) { fa[f] = sim; fb[f] = swt; }
            else                     { fa[f] = swt; fb[f] = sim; }
        }
#pragma unroll
        for (int fm = 0; fm < 4; ++fm)
#pragma unroll
            for (int fn = 0; fn < 4; ++fn)
                acc[fm][fn] = __builtin_amdgcn_mfma_f32_16x16x32_bf16(fa[fm], fb[fn], acc[fm][fn], 0, 0, 0);
        __syncthreads();
    }

    // epilogue: C layout col = lane&15, row = (lane>>4)*4 + reg
    if constexpr (MODE == 0) {
        u16* outp = (blockIdx.z == 0) ? q : (blockIdx.z == 1) ? k : v;
#pragma unroll
        for (int fm = 0; fm < 4; ++fm)
#pragma unroll
            for (int fn = 0; fn < 4; ++fn)
#pragma unroll
                for (int r = 0; r < 4; ++r) {
                    int row = imbase + wr * 64 + fm * 16 + (l >> 4) * 4 + r;
                    int col = cobase + wc * 64 + fn * 16 + (l & 15);
                    outp[(size_t)row * 512 + col] = f2bf(acc[fm][fn][r]);
                }
    } else {
#pragma unroll
        for (int fm = 0; fm < 4; ++fm)
#pragma unroll
            for (int fn = 0; fn < 4; ++fn)
#pragma unroll
                for (int r = 0; r < 4; ++r) {
                    int co = cobase + wr * 64 + fm * 16 + (l >> 4) * 4 + r;
                    int imrow = imbase + wc * 64 + fn * 16 + (l & 15);
                    int n = imrow >> 8, p = imrow & 255;
                    size_t addr = (((size_t)(n * 512 + co)) << 8) + p;
                    out[addr] = acc[fm][fn][r] + xres[addr];
                }
    }
}

// ---------------------------------------------------------------------------
// attention per pixel (bf16 in, bf16 out in place of v)
// ---------------------------------------------------------------------------
__global__ __launch_bounds__(256) void attn_kernel(
    const u16* __restrict__ qT, const u16* __restrict__ kT, u16* vvT)
{
    const int p = blockIdx.x;
    const int t = threadIdx.x;
    __shared__ float smemA[2][64][68];
    __shared__ float attb[64][68];
    const size_t pb = (size_t)p * (NB * CCH);

    const int ng = t >> 4, mg = t & 15;
    const int n0 = ng * 4, m0 = mg * 4;
    float acc[4][4];
#pragma unroll
    for (int i = 0; i < 4; ++i)
#pragma unroll
        for (int j = 0; j < 4; ++j) acc[i][j] = 0.f;

    for (int ct = 0; ct < 8; ++ct) {
        const int c0 = ct * 64;
        __syncthreads();
#pragma unroll
        for (int s = 0; s < 2; ++s) {
            int f = t + s * 256;
            int nn = f >> 3, c8 = (f & 7) * 8;
            short8 qv = *(const short8*)(qT + pb + (size_t)nn * CCH + c0 + c8);
            short8 kv = *(const short8*)(kT + pb + (size_t)nn * CCH + c0 + c8);
#pragma unroll
            for (int e = 0; e < 8; ++e) {
                smemA[0][nn][c8 + e] = bf2f((u16)qv[e]);
                smemA[1][nn][c8 + e] = bf2f((u16)kv[e]);
            }
        }
        __syncthreads();
#pragma unroll 4
        for (int c4 = 0; c4 < 16; ++c4) {
            float4 q4[4], k4[4];
#pragma unroll
            for (int i = 0; i < 4; ++i) q4[i] = *(const float4*)&smemA[0][n0 + i][c4 * 4];
#pragma unroll
            for (int j = 0; j < 4; ++j) k4[j] = *(const float4*)&smemA[1][m0 + j][c4 * 4];
#pragma unroll
            for (int i = 0; i < 4; ++i)
#pragma unroll
                for (int j = 0; j < 4; ++j) {
                    acc[i][j] = fmaf(q4[i].x, k4[j].x, acc[i][j]);
                    acc[i][j] = fmaf(q4[i].y, k4[j].y, acc[i][j]);
                    acc[i][j] = fmaf(q4[i].z, k4[j].z, acc[i][j]);
                    acc[i][j] = fmaf(q4[i].w, k4[j].w, acc[i][j]);
                }
        }
    }

    const float SCALE = 0.0441941738241592f;  // 1/sqrt(512)
#pragma unroll
    for (int i = 0; i < 4; ++i) {
        float m = fmaxf(fmaxf(acc[i][0], acc[i][1]), fmaxf(acc[i][2], acc[i][3]));
#pragma unroll
        for (int mask = 1; mask < 16; mask <<= 1) m = fmaxf(m, __shfl_xor(m, mask, 16));
        float e[4]; float s = 0.f;
#pragma unroll
        for (int j = 0; j < 4; ++j) { e[j] = __expf((acc[i][j] - m) * SCALE); s += e[j]; }
#pragma unroll
        for (int mask = 1; mask < 16; mask <<= 1) s += __shfl_xor(s, mask, 16);
        float inv = 1.f / s;
#pragma unroll
        for (int j = 0; j < 4; ++j) attb[n0 + i][m0 + j] = e[j] * inv;
    }
    __syncthreads();

    float* vs = &smemA[0][0][0];  // vs[m*132 + c]
    const int ng2 = t >> 3, cg = t & 7;
    const int nn0 = ng2 * 2, cb = cg * 16;
    for (int ct4 = 0; ct4 < 4; ++ct4) {
        const int c0 = ct4 * 128;
#pragma unroll
        for (int s = 0; s < 4; ++s) {
            int f = t + s * 256;
            int m = f >> 4, c8 = (f & 15) * 8;
            short8 vv = *(const short8*)(vvT + pb + (size_t)m * CCH + c0 + c8);
#pragma unroll
            for (int e = 0; e < 8; ++e) vs[m * 132 + c8 + e] = bf2f((u16)vv[e]);
        }
        __syncthreads();
        float acc2[2][16];
#pragma unroll
        for (int i = 0; i < 2; ++i)
#pragma unroll
            for (int j = 0; j < 16; ++j) acc2[i][j] = 0.f;
#pragma unroll 4
        for (int m = 0; m < 64; ++m) {
            float a0 = attb[nn0][m], a1 = attb[nn0 + 1][m];
#pragma unroll
            for (int k4 = 0; k4 < 4; ++k4) {
                float4 v4 = *(const float4*)&vs[m * 132 + cb + k4 * 4];
                acc2[0][k4 * 4 + 0] = fmaf(a0, v4.x, acc2[0][k4 * 4 + 0]);
                acc2[0][k4 * 4 + 1] = fmaf(a0, v4.y, acc2[0][k4 * 4 + 1]);
                acc2[0][k4 * 4 + 2] = fmaf(a0, v4.z, acc2[0][k4 * 4 + 2]);
                acc2[0][k4 * 4 + 3] = fmaf(a0, v4.w, acc2[0][k4 * 4 + 3]);
                acc2[1][k4 * 4 + 0] = fmaf(a1, v4.x, acc2[1][k4 * 4 + 0]);
                acc2[1][k4 * 4 + 1] = fmaf(a1, v4.y, acc2[1][k4 * 4 + 1]);
                acc2[1][k4 * 4 + 2] = fmaf(a1, v4.z, acc2[1][k4 * 4 + 2]);
                acc2[1][k4 * 4 + 3] = fmaf(a1, v4.w, acc2[1][k4 * 4 + 3]);
            }
        }
#pragma unroll
        for (int i = 0; i < 2; ++i)
#pragma unroll
            for (int j = 0; j < 16; ++j)
                vvT[pb + (size_t)(nn0 + i) * CCH + c0 + cb + j] = f2bf(acc2[i][j]);
        __syncthreads();
    }
}

// ---------------------------------------------------------------------------
// GroupNorm(1,C)+affine+ReLU: virt bf16 [p][n][c] -> ypad bf16 [n][18][18][c]
// ---------------------------------------------------------------------------
__global__ __launch_bounds__(256) void gn_kernel(
    const u16* __restrict__ virtT, const float* __restrict__ gamma,
    const float* __restrict__ beta, u16* __restrict__ ypad)
{
    const int n = blockIdx.x, t = threadIdx.x;
    __shared__ float sg[512], sb[512];
    for (int i = t; i < 512; i += 256) { sg[i] = gamma[i]; sb[i] = beta[i]; }

    float sum = 0.f, ss = 0.f;
    for (int it = 0; it < 64; ++it) {
        int f = t + it * 256;
        int p = f >> 6, c = (f & 63) * 8;
        short8 vv = *(const short8*)(virtT + ((size_t)(p * 64 + n)) * 512 + c);
#pragma unroll
        for (int e = 0; e < 8; ++e) { float x = bf2f((u16)vv[e]); sum += x; ss = fmaf(x, x, ss); }
    }
#pragma unroll
    for (int off = 32; off > 0; off >>= 1) {
        sum += __shfl_down(sum, off);
        ss  += __shfl_down(ss, off);
    }
    __shared__ float rs[4], rss[4], stats[2];
    const int wid = t >> 6, lane = t & 63;
    if (lane == 0) { rs[wid] = sum; rss[wid] = ss; }
    __syncthreads();
    if (t == 0) {
        float S = rs[0] + rs[1] + rs[2] + rs[3];
        float SS = rss[0] + rss[1] + rss[2] + rss[3];
        float mu = S * (1.f / 131072.f);
        float var = SS * (1.f / 131072.f) - mu * mu;
        stats[0] = mu;
        stats[1] = rsqrtf(var + 1e-5f);
    }
    __syncthreads();
    const float mu = stats[0], rstd = stats[1];

    for (int it = 0; it < 64; ++it) {
        int f = t + it * 256;
        int p = f >> 6, cc = (f & 63) * 8;
        short8 vv = *(const short8*)(virtT + ((size_t)(p * 64 + n)) * 512 + cc);
        short8 ov;
#pragma unroll
        for (int e = 0; e < 8; ++e) {
            float x = (bf2f((u16)vv[e]) - mu) * rstd;
            x = fmaf(x, sg[cc + e], sb[cc + e]);
            ov[e] = (short)f2bf(fmaxf(x, 0.f));
        }
        int h = p >> 4, wcol = p & 15;
        *(short8*)(ypad + ((size_t)((n * 18 + h + 1) * 18 + wcol + 1)) * 512 + cc) = ov;
    }
}

// ---------------------------------------------------------------------------
extern "C" void kernel_launch(void* const* d_in, const int* in_sizes, int n_in,
                              void* d_out, int out_size, void* d_ws, size_t ws_size,
                              hipStream_t stream)
{
    const float* x     = (const float*)d_in[0];
    const float* Wq    = (const float*)d_in[1];
    const float* Wk    = (const float*)d_in[2];
    const float* Wv    = (const float*)d_in[3];
    const float* Wc    = (const float*)d_in[4];
    const float* gamma = (const float*)d_in[5];
    const float* beta  = (const float*)d_in[6];
    float* out = (float*)d_out;

    // workspace (u16 units): pad 10,616,832 | Wt 9,437,184 | q,k,v 3x8,388,608
    // total 90,439,680 bytes * ... = 90.4 MB
    u16* pad = (u16*)d_ws;
    u16* Wt  = pad + 10616832;
    u16* q   = Wt + 9437184;
    u16* k   = q + 8388608;
    u16* v   = k + 8388608;   // virt written in place after PV

    zero_borders<<<dim3(64), dim3(256), 0, stream>>>(pad);
    prep_x<<<dim3(4, 8, 64), dim3(256), 0, stream>>>(x, pad);
    prep_w<<<dim3(512, 4), dim3(256), 0, stream>>>(Wq, Wk, Wv, Wc, Wt);

    conv_mfma<0><<<dim3(4, 128, 3), dim3(256), 0, stream>>>(pad, Wt, q, k, v, nullptr, nullptr);
    attn_kernel<<<dim3(256), dim3(256), 0, stream>>>(q, k, v);
    gn_kernel<<<dim3(64), dim3(256), 0, stream>>>(v, gamma, beta, pad);
    conv_mfma<1><<<dim3(128, 4, 1), dim3(256), 0, stream>>>(pad, Wt + 3 * 2359296, nullptr, nullptr, nullptr, x, out);
}

// Round 3
// 463.582 us; speedup vs baseline: 9.8912x; 1.1192x over previous
//
#include <hip/hip_runtime.h>
#include <math.h>

typedef unsigned short u16;
typedef unsigned int u32;
typedef short short8 __attribute__((ext_vector_type(8)));
typedef float f32x4 __attribute__((ext_vector_type(4)));

#define NB 64
#define CCH 512
#define HW 256

// ---- bf16 helpers (bit-level, RNE) ----
__device__ __forceinline__ u16 f2bf(float f) {
    union { float f; u32 u; } x; x.f = f;
    u32 r = x.u + 0x7fffu + ((x.u >> 16) & 1u);
    return (u16)(r >> 16);
}
__device__ __forceinline__ float bf2f(u16 b) {
    union { u32 u; float f; } x; x.u = ((u32)b) << 16;
    return x.f;
}
__device__ __forceinline__ void gload_lds16(const u16* g, u16* l) {
    __builtin_amdgcn_global_load_lds((const __attribute__((address_space(1))) u32*)g,
                                     (__attribute__((address_space(3))) u32*)l, 16, 0, 0);
}

// ---------------------------------------------------------------------------
// zero the padded-image border cells (68 cells/sample x 512 c)
// ---------------------------------------------------------------------------
__global__ __launch_bounds__(256) void zero_borders(u16* __restrict__ pad) {
    const int n = blockIdx.x, t = threadIdx.x;
    short8 z = (short8){0,0,0,0,0,0,0,0};
    for (int idx = t; idx < 68 * 64; idx += 256) {
        int cell = idx >> 6, ch = idx & 63;
        int hh, ww;
        if (cell < 18)      { hh = 0;          ww = cell; }
        else if (cell < 36) { hh = 17;         ww = cell - 18; }
        else if (cell < 52) { hh = cell - 35;  ww = 0; }
        else                { hh = cell - 51;  ww = 17; }
        *(short8*)(pad + ((size_t)((n * 18 + hh) * 18 + ww)) * 512 + ch * 8) = z;
    }
}

// ---------------------------------------------------------------------------
// NCHW fp32 -> padded pixel-major bf16 [n][18][18][512] (interior only)
// ---------------------------------------------------------------------------
__global__ __launch_bounds__(256) void prep_x(const float* __restrict__ x, u16* __restrict__ pad) {
    __shared__ float tl[64][65];
    const int n = blockIdx.z, c0 = blockIdx.y * 64, p0 = blockIdx.x * 64;
    const int t = threadIdx.x;
    {
        const int cc = t >> 2, ps = (t & 3) * 16;
#pragma unroll
        for (int i = 0; i < 4; ++i) {
            float4 v4 = *(const float4*)(x + (((size_t)(n * 512 + c0 + cc)) << 8) + p0 + ps + i * 4);
            tl[cc][ps + i * 4 + 0] = v4.x;
            tl[cc][ps + i * 4 + 1] = v4.y;
            tl[cc][ps + i * 4 + 2] = v4.z;
            tl[cc][ps + i * 4 + 3] = v4.w;
        }
    }
    __syncthreads();
    {
        const int pp = t >> 2, cs = (t & 3) * 16;
        short8 o0, o1;
#pragma unroll
        for (int i = 0; i < 8; ++i) o0[i] = (short)f2bf(tl[cs + i][pp]);
#pragma unroll
        for (int i = 0; i < 8; ++i) o1[i] = (short)f2bf(tl[cs + 8 + i][pp]);
        const int p = p0 + pp, h = p >> 4, wcol = p & 15;
        u16* dst = pad + ((size_t)((n * 18 + h + 1) * 18 + wcol + 1)) * 512 + c0 + cs;
        *(short8*)(dst + 0) = o0;
        *(short8*)(dst + 8) = o1;
    }
}

// ---------------------------------------------------------------------------
// weights fp32 [co][ci][3][3] -> bf16 Wt[sel][tap][co][ci]
// ---------------------------------------------------------------------------
__global__ __launch_bounds__(256) void prep_w(
    const float* __restrict__ Wq, const float* __restrict__ Wk,
    const float* __restrict__ Wv, const float* __restrict__ Wc,
    u16* __restrict__ Wt)
{
    __shared__ float lw[4608];
    const int co = blockIdx.x, sel = blockIdx.y, t = threadIdx.x;
    const float* Ws = (sel == 0) ? Wq : (sel == 1) ? Wk : (sel == 2) ? Wv : Wc;
#pragma unroll
    for (int i = 0; i < 18; ++i) lw[t + i * 256] = Ws[(size_t)co * 4608 + t + i * 256];
    __syncthreads();
    for (int tap = 0; tap < 9; ++tap)
#pragma unroll
        for (int hh = 0; hh < 2; ++hh) {
            int ci = t + hh * 256;
            Wt[(((size_t)(sel * 9 + tap)) << 18) + (co << 9) + ci] = f2bf(lw[ci * 9 + tap]);
        }
}

// ---------------------------------------------------------------------------
// Fused QKV conv3x3 implicit GEMM: M=16384 imrows (p-major), N=1536 (q|k|v co),
// K=4608 (9 taps x 512). BM=256, BN=192, BK=32. 512 thr = 8 waves (2M x 4N),
// wave tile 128x48 (8x3 frags of 16x16). Triple-buffered LDS, 2 phases/K-tile,
// counted vmcnt (stages for kt+2 issued during kt), raw s_barrier, setprio.
// LDS chunk swizzle: phys16Bchunk = logical ^ ((row>>2)&3), both sides.
// ---------------------------------------------------------------------------
__global__ __launch_bounds__(512, 1) void qkv_mfma8(
    const u16* __restrict__ pad, const u16* __restrict__ Wt,
    u16* __restrict__ q, u16* __restrict__ k, u16* __restrict__ v)
{
    __shared__ short As[3][8192];   // [256 rows][32 k] per buf, 16KB
    __shared__ short Bs[3][6144];   // [192 rows][32 k] per buf, 12KB
    const int t = threadIdx.x;
    const int l = t & 63;
    const int wid = t >> 6;
    const int wm = wid >> 2, wn = wid & 3;

    // XCD-bijective block swizzle (512 blocks, 8 XCDs)
    const int o = blockIdx.x;
    const int wg = (o & 7) * 64 + (o >> 3);
    const int imbase = (wg >> 3) * 256;
    const int cobase = (wg & 7) * 192;

    // ---- staging address precompute ----
    // stage unit = 1KB by one wave: 16 rows x 64B. A: units 0..15, B: units 0..11.
    const int cl = (l & 3) ^ ((l >> 4) & 3);   // logical 16B chunk this lane fetches
    int imoffA[2], woffB[2];
#pragma unroll
    for (int rr = 0; rr < 2; ++rr) {
        const int chunk = wid * 2 + rr;
        const int imrow = imbase + chunk * 16 + (l >> 2);
        const int p = imrow >> 6, n = imrow & 63;
        imoffA[rr] = ((n * 18 + (p >> 4)) * 18 + (p & 15)) * 512 + cl * 8;
        const int cof = cobase + chunk * 16 + (l >> 2);
        const int sel = cof >> 9, co = cof & 511;
        woffB[rr] = sel * 9 * 262144 + co * 512 + cl * 8;   // only used if wid<6
    }

    // ---- fragment read offsets (swizzled) ----
    const int fragchunk = ((l >> 4) ^ (l >> 2)) & 3;
    const int aoff = (wm * 128 + (l & 15)) * 32 + fragchunk * 8;
    const int boff = (wn * 48 + (l & 15)) * 32 + fragchunk * 8;

    f32x4 acc[8][3];
#pragma unroll
    for (int i = 0; i < 8; ++i)
#pragma unroll
        for (int j = 0; j < 3; ++j) acc[i][j] = (f32x4){0.f, 0.f, 0.f, 0.f};

    auto STAGE_A = [&](int kt, int s) {
        const int tap = kt >> 4;
        const int shift = ((tap / 3) * 18 + (tap % 3)) * 512 + (kt & 15) * 32;
#pragma unroll
        for (int rr = 0; rr < 2; ++rr)
            gload_lds16(pad + imoffA[rr] + shift, (u16*)(&As[s][0] + (wid * 2 + rr) * 512));
    };
    auto STAGE_B = [&](int kt, int s) {
        if (wid < 6) {
            const int tap = kt >> 4;
            const int shift = tap * 262144 + (kt & 15) * 32;
#pragma unroll
            for (int rr = 0; rr < 2; ++rr)
                gload_lds16(Wt + woffB[rr] + shift, (u16*)(&Bs[s][0] + (wid * 2 + rr) * 512));
        }
    };

    // prologue: stage kt=0 and kt=1
    STAGE_A(0, 0); STAGE_B(0, 0);
    STAGE_A(1, 1); STAGE_B(1, 1);
    if (wid < 6) asm volatile("s_waitcnt vmcnt(4)" ::: "memory");
    else         asm volatile("s_waitcnt vmcnt(2)" ::: "memory");
    __builtin_amdgcn_sched_barrier(0);
    __builtin_amdgcn_s_barrier();

    int s0 = 0;
    short8 fa[4], fb[3];
#pragma unroll 1
    for (int kt = 0; kt < 144; ++kt) {
        const int s2 = (s0 == 0) ? 2 : s0 - 1;    // (kt+2)%3
        const short* Ab = &As[s0][0];
        const short* Bb = &Bs[s0][0];

        // ================= Phase 0 =================
#pragma unroll
        for (int j = 0; j < 3; ++j) fb[j] = *(const short8*)(Bb + boff + j * 512);
#pragma unroll
        for (int i = 0; i < 4; ++i) fa[i] = *(const short8*)(Ab + aoff + i * 512);
        if (kt < 142) STAGE_A(kt + 2, s2);
        __builtin_amdgcn_sched_barrier(0);
        __builtin_amdgcn_s_barrier();
        asm volatile("s_waitcnt lgkmcnt(0)" ::: "memory");
        __builtin_amdgcn_sched_barrier(0);
        __builtin_amdgcn_s_setprio(1);
#pragma unroll
        for (int i = 0; i < 4; ++i)
#pragma unroll
            for (int j = 0; j < 3; ++j)
                acc[i][j] = __builtin_amdgcn_mfma_f32_16x16x32_bf16(fa[i], fb[j], acc[i][j], 0, 0, 0);
        __builtin_amdgcn_s_setprio(0);
        __builtin_amdgcn_sched_barrier(0);
        __builtin_amdgcn_s_barrier();

        // ================= Phase 1 =================
#pragma unroll
        for (int i = 0; i < 4; ++i) fa[i] = *(const short8*)(Ab + aoff + 2048 + i * 512);
        if (kt < 142) STAGE_B(kt + 2, s2);
        __builtin_amdgcn_sched_barrier(0);
        __builtin_amdgcn_s_barrier();
        asm volatile("s_waitcnt lgkmcnt(0)" ::: "memory");
        __builtin_amdgcn_sched_barrier(0);
        __builtin_amdgcn_s_setprio(1);
#pragma unroll
        for (int i = 0; i < 4; ++i)
#pragma unroll
            for (int j = 0; j < 3; ++j)
                acc[4 + i][j] = __builtin_amdgcn_mfma_f32_16x16x32_bf16(fa[i], fb[j], acc[4 + i][j], 0, 0, 0);
        __builtin_amdgcn_s_setprio(0);
        // boundary: everything older than the kt+2 stages must be landed
        if (kt < 142) {
            if (wid < 6) asm volatile("s_waitcnt vmcnt(4)" ::: "memory");
            else         asm volatile("s_waitcnt vmcnt(2)" ::: "memory");
        } else {
            asm volatile("s_waitcnt vmcnt(0)" ::: "memory");
        }
        __builtin_amdgcn_sched_barrier(0);
        __builtin_amdgcn_s_barrier();

        s0 = (s0 == 2) ? 0 : s0 + 1;
    }

    // epilogue: C layout col = lane&15, row = (lane>>4)*4 + reg
#pragma unroll
    for (int j = 0; j < 3; ++j) {
        const int colb = cobase + wn * 48 + j * 16;
        u16* op = ((colb >> 9) == 0) ? q : (((colb >> 9) == 1) ? k : v);
        op += (colb & 511) + (l & 15);
#pragma unroll
        for (int i = 0; i < 8; ++i) {
            const int row = imbase + wm * 128 + i * 16 + (l >> 4) * 4;
#pragma unroll
            for (int r = 0; r < 4; ++r)
                op[(size_t)(row + r) * 512] = f2bf(acc[i][j][r]);
        }
    }
}

// ---------------------------------------------------------------------------
// final conv3x3 + residual (old verified 128x128 m97-style structure)
// M=co, N=im-rows (n-major); out NCHW fp32 + residual. grid (x=128, y=4)
// ---------------------------------------------------------------------------
__global__ __launch_bounds__(256, 2) void cres_mfma(
    const u16* __restrict__ pad, const u16* __restrict__ Wt,
    const float* __restrict__ xres, float* __restrict__ out)
{
    __shared__ short bufA[2][4096];
    __shared__ short bufB[2][4096];
    const int t = threadIdx.x;
    const int l = t & 63;
    const int w = t >> 6;
    const int wr = w >> 1, wc = w & 1;

    const int imbase = blockIdx.x * 128;
    const int cobase = blockIdx.y * 128;

    const int lr = l >> 2;
    const int cl = (l & 3) ^ ((l >> 2) & 3) ^ ((l >> 4) & 3);
    int imoff[2], woff[2];
#pragma unroll
    for (int i = 0; i < 2; ++i) {
        int r = w * 32 + i * 16 + lr;
        int imrow = imbase + r;
        int n = imrow >> 8, p = imrow & 255;
        int h = p >> 4, wco = p & 15;
        imoff[i] = ((n * 18 + h) * 18 + wco) * 512 + cl * 8;
        woff[i]  = (cobase + r) * 512 + cl * 8;
    }
    const int sw = (l & 3) ^ ((l >> 2) & 3);
    const int fragoff = (l & 15) * 32 + (((l >> 4) ^ sw) & 3) * 8;

    f32x4 acc[4][4];
#pragma unroll
    for (int a = 0; a < 4; ++a)
#pragma unroll
        for (int b = 0; b < 4; ++b) acc[a][b] = (f32x4){0.f, 0.f, 0.f, 0.f};

    auto STAGE = [&](int s, int j, int k0) {
        const int shift = ((j / 3) * 18 + (j % 3)) * 512 + k0;
        const size_t wjo = ((size_t)j << 18) + k0;
#pragma unroll
        for (int i = 0; i < 2; ++i) {
            gload_lds16(pad + imoff[i] + shift, (u16*)&bufA[s][(w * 32 + i * 16) * 32]);
            gload_lds16(Wt + woff[i]  + wjo,   (u16*)&bufB[s][(w * 32 + i * 16) * 32]);
        }
    };

    STAGE(0, 0, 0);
    __syncthreads();

    for (int kt = 0; kt < 144; ++kt) {
        const int cur = kt & 1;
        if (kt < 143) {
            const int kn = kt + 1;
            STAGE(cur ^ 1, kn >> 4, (kn & 15) * 32);
        }
        short8 fa[4], fb[4];
        const short* IMb = &bufA[cur][0];
        const short* Wb  = &bufB[cur][0];
#pragma unroll
        for (int f = 0; f < 4; ++f) {
            const int imr = wc * 64 + f * 16;
            const int wrr = wr * 64 + f * 16;
            fb[f] = *(const short8*)(IMb + imr * 32 + fragoff);
            fa[f] = *(const short8*)(Wb  + wrr * 32 + fragoff);
        }
#pragma unroll
        for (int fm = 0; fm < 4; ++fm)
#pragma unroll
            for (int fn = 0; fn < 4; ++fn)
                acc[fm][fn] = __builtin_amdgcn_mfma_f32_16x16x32_bf16(fa[fm], fb[fn], acc[fm][fn], 0, 0, 0);
        __syncthreads();
    }

#pragma unroll
    for (int fm = 0; fm < 4; ++fm)
#pragma unroll
        for (int fn = 0; fn < 4; ++fn)
#pragma unroll
            for (int r = 0; r < 4; ++r) {
                int co = cobase + wr * 64 + fm * 16 + (l >> 4) * 4 + r;
                int imrow = imbase + wc * 64 + fn * 16 + (l & 15);
                int n = imrow >> 8, p = imrow & 255;
                size_t addr = (((size_t)(n * 512 + co)) << 8) + p;
                out[addr] = acc[fm][fn][r] + xres[addr];
            }
}

// ---------------------------------------------------------------------------
// attention per pixel (bf16 in, bf16 out in place of v)
// ---------------------------------------------------------------------------
__global__ __launch_bounds__(256) void attn_kernel(
    const u16* __restrict__ qT, const u16* __restrict__ kT, u16* vvT)
{
    const int p = blockIdx.x;
    const int t = threadIdx.x;
    __shared__ float smemA[2][64][68];
    __shared__ float attb[64][68];
    const size_t pb = (size_t)p * (NB * CCH);

    const int ng = t >> 4, mg = t & 15;
    const int n0 = ng * 4, m0 = mg * 4;
    float acc[4][4];
#pragma unroll
    for (int i = 0; i < 4; ++i)
#pragma unroll
        for (int j = 0; j < 4; ++j) acc[i][j] = 0.f;

    for (int ct = 0; ct < 8; ++ct) {
        const int c0 = ct * 64;
        __syncthreads();
#pragma unroll
        for (int s = 0; s < 2; ++s) {
            int f = t + s * 256;
            int nn = f >> 3, c8 = (f & 7) * 8;
            short8 qv = *(const short8*)(qT + pb + (size_t)nn * CCH + c0 + c8);
            short8 kv = *(const short8*)(kT + pb + (size_t)nn * CCH + c0 + c8);
#pragma unroll
            for (int e = 0; e < 8; ++e) {
                smemA[0][nn][c8 + e] = bf2f((u16)qv[e]);
                smemA[1][nn][c8 + e] = bf2f((u16)kv[e]);
            }
        }
        __syncthreads();
#pragma unroll 4
        for (int c4 = 0; c4 < 16; ++c4) {
            float4 q4[4], k4[4];
#pragma unroll
            for (int i = 0; i < 4; ++i) q4[i] = *(const float4*)&smemA[0][n0 + i][c4 * 4];
#pragma unroll
            for (int j = 0; j < 4; ++j) k4[j] = *(const float4*)&smemA[1][m0 + j][c4 * 4];
#pragma unroll
            for (int i = 0; i < 4; ++i)
#pragma unroll
                for (int j = 0; j < 4; ++j) {
                    acc[i][j] = fmaf(q4[i].x, k4[j].x, acc[i][j]);
                    acc[i][j] = fmaf(q4[i].y, k4[j].y, acc[i][j]);
                    acc[i][j] = fmaf(q4[i].z, k4[j].z, acc[i][j]);
                    acc[i][j] = fmaf(q4[i].w, k4[j].w, acc[i][j]);
                }
        }
    }

    const float SCALE = 0.0441941738241592f;  // 1/sqrt(512)
#pragma unroll
    for (int i = 0; i < 4; ++i) {
        float m = fmaxf(fmaxf(acc[i][0], acc[i][1]), fmaxf(acc[i][2], acc[i][3]));
#pragma unroll
        for (int mask = 1; mask < 16; mask <<= 1) m = fmaxf(m, __shfl_xor(m, mask, 16));
        float e[4]; float s = 0.f;
#pragma unroll
        for (int j = 0; j < 4; ++j) { e[j] = __expf((acc[i][j] - m) * SCALE); s += e[j]; }
#pragma unroll
        for (int mask = 1; mask < 16; mask <<= 1) s += __shfl_xor(s, mask, 16);
        float inv = 1.f / s;
#pragma unroll
        for (int j = 0; j < 4; ++j) attb[n0 + i][m0 + j] = e[j] * inv;
    }
    __syncthreads();

    float* vs = &smemA[0][0][0];  // vs[m*132 + c]
    const int ng2 = t >> 3, cg = t & 7;
    const int nn0 = ng2 * 2, cb = cg * 16;
    for (int ct4 = 0; ct4 < 4; ++ct4) {
        const int c0 = ct4 * 128;
#pragma unroll
        for (int s = 0; s < 4; ++s) {
            int f = t + s * 256;
            int m = f >> 4, c8 = (f & 15) * 8;
            short8 vv = *(const short8*)(vvT + pb + (size_t)m * CCH + c0 + c8);
#pragma unroll
            for (int e = 0; e < 8; ++e) vs[m * 132 + c8 + e] = bf2f((u16)vv[e]);
        }
        __syncthreads();
        float acc2[2][16];
#pragma unroll
        for (int i = 0; i < 2; ++i)
#pragma unroll
            for (int j = 0; j < 16; ++j) acc2[i][j] = 0.f;
#pragma unroll 4
        for (int m = 0; m < 64; ++m) {
            float a0 = attb[nn0][m], a1 = attb[nn0 + 1][m];
#pragma unroll
            for (int k4 = 0; k4 < 4; ++k4) {
                float4 v4 = *(const float4*)&vs[m * 132 + cb + k4 * 4];
                acc2[0][k4 * 4 + 0] = fmaf(a0, v4.x, acc2[0][k4 * 4 + 0]);
                acc2[0][k4 * 4 + 1] = fmaf(a0, v4.y, acc2[0][k4 * 4 + 1]);
                acc2[0][k4 * 4 + 2] = fmaf(a0, v4.z, acc2[0][k4 * 4 + 2]);
                acc2[0][k4 * 4 + 3] = fmaf(a0, v4.w, acc2[0][k4 * 4 + 3]);
                acc2[1][k4 * 4 + 0] = fmaf(a1, v4.x, acc2[1][k4 * 4 + 0]);
                acc2[1][k4 * 4 + 1] = fmaf(a1, v4.y, acc2[1][k4 * 4 + 1]);
                acc2[1][k4 * 4 + 2] = fmaf(a1, v4.z, acc2[1][k4 * 4 + 2]);
                acc2[1][k4 * 4 + 3] = fmaf(a1, v4.w, acc2[1][k4 * 4 + 3]);
            }
        }
#pragma unroll
        for (int i = 0; i < 2; ++i)
#pragma unroll
            for (int j = 0; j < 16; ++j)
                vvT[pb + (size_t)(nn0 + i) * CCH + c0 + cb + j] = f2bf(acc2[i][j]);
        __syncthreads();
    }
}

// ---------------------------------------------------------------------------
// GroupNorm(1,C)+affine+ReLU: virt bf16 [p][n][c] -> ypad bf16 [n][18][18][c]
// ---------------------------------------------------------------------------
__global__ __launch_bounds__(256) void gn_kernel(
    const u16* __restrict__ virtT, const float* __restrict__ gamma,
    const float* __restrict__ beta, u16* __restrict__ ypad)
{
    const int n = blockIdx.x, t = threadIdx.x;
    __shared__ float sg[512], sb[512];
    for (int i = t; i < 512; i += 256) { sg[i] = gamma[i]; sb[i] = beta[i]; }

    float sum = 0.f, ss = 0.f;
    for (int it = 0; it < 64; ++it) {
        int f = t + it * 256;
        int p = f >> 6, c = (f & 63) * 8;
        short8 vv = *(const short8*)(virtT + ((size_t)(p * 64 + n)) * 512 + c);
#pragma unroll
        for (int e = 0; e < 8; ++e) { float x = bf2f((u16)vv[e]); sum += x; ss = fmaf(x, x, ss); }
    }
#pragma unroll
    for (int off = 32; off > 0; off >>= 1) {
        sum += __shfl_down(sum, off);
        ss  += __shfl_down(ss, off);
    }
    __shared__ float rs[4], rss[4], stats[2];
    const int wid = t >> 6, lane = t & 63;
    if (lane == 0) { rs[wid] = sum; rss[wid] = ss; }
    __syncthreads();
    if (t == 0) {
        float S = rs[0] + rs[1] + rs[2] + rs[3];
        float SS = rss[0] + rss[1] + rss[2] + rss[3];
        float mu = S * (1.f / 131072.f);
        float var = SS * (1.f / 131072.f) - mu * mu;
        stats[0] = mu;
        stats[1] = rsqrtf(var + 1e-5f);
    }
    __syncthreads();
    const float mu = stats[0], rstd = stats[1];

    for (int it = 0; it < 64; ++it) {
        int f = t + it * 256;
        int p = f >> 6, cc = (f & 63) * 8;
        short8 vv = *(const short8*)(virtT + ((size_t)(p * 64 + n)) * 512 + cc);
        short8 ov;
#pragma unroll
        for (int e = 0; e < 8; ++e) {
            float x = (bf2f((u16)vv[e]) - mu) * rstd;
            x = fmaf(x, sg[cc + e], sb[cc + e]);
            ov[e] = (short)f2bf(fmaxf(x, 0.f));
        }
        int h = p >> 4, wcol = p & 15;
        *(short8*)(ypad + ((size_t)((n * 18 + h + 1) * 18 + wcol + 1)) * 512 + cc) = ov;
    }
}

// ---------------------------------------------------------------------------
extern "C" void kernel_launch(void* const* d_in, const int* in_sizes, int n_in,
                              void* d_out, int out_size, void* d_ws, size_t ws_size,
                              hipStream_t stream)
{
    const float* x     = (const float*)d_in[0];
    const float* Wq    = (const float*)d_in[1];
    const float* Wk    = (const float*)d_in[2];
    const float* Wv    = (const float*)d_in[3];
    const float* Wc    = (const float*)d_in[4];
    const float* gamma = (const float*)d_in[5];
    const float* beta  = (const float*)d_in[6];
    float* out = (float*)d_out;

    // workspace (u16 units): pad | Wt | q | k | v  (~90.4 MB total)
    u16* pad = (u16*)d_ws;
    u16* Wt  = pad + 10616832;
    u16* q   = Wt + 9437184;
    u16* k   = q + 8388608;
    u16* v   = k + 8388608;   // virt written in place after PV

    zero_borders<<<dim3(64), dim3(256), 0, stream>>>(pad);
    prep_x<<<dim3(4, 8, 64), dim3(256), 0, stream>>>(x, pad);
    prep_w<<<dim3(512, 4), dim3(256), 0, stream>>>(Wq, Wk, Wv, Wc, Wt);

    qkv_mfma8<<<dim3(512), dim3(512), 0, stream>>>(pad, Wt, q, k, v);
    attn_kernel<<<dim3(256), dim3(256), 0, stream>>>(q, k, v);
    gn_kernel<<<dim3(64), dim3(256), 0, stream>>>(v, gamma, beta, pad);
    cres_mfma<<<dim3(128, 4), dim3(256), 0, stream>>>(pad, Wt + 3 * 2359296, x, out);
}

// Round 4
// 427.803 us; speedup vs baseline: 10.7185x; 1.0836x over previous
//
#include <hip/hip_runtime.h>
#include <math.h>

typedef unsigned short u16;
typedef unsigned int u32;
typedef short short8 __attribute__((ext_vector_type(8)));
typedef float f32x4 __attribute__((ext_vector_type(4)));

#define NB 64
#define CCH 512
#define HW 256

// ---- bf16 helpers (bit-level, RNE) ----
__device__ __forceinline__ u16 f2bf(float f) {
    union { float f; u32 u; } x; x.f = f;
    u32 r = x.u + 0x7fffu + ((x.u >> 16) & 1u);
    return (u16)(r >> 16);
}
__device__ __forceinline__ float bf2f(u16 b) {
    union { u32 u; float f; } x; x.u = ((u32)b) << 16;
    return x.f;
}
__device__ __forceinline__ void gload_lds16(const u16* g, u16* l) {
    __builtin_amdgcn_global_load_lds((const __attribute__((address_space(1))) u32*)g,
                                     (__attribute__((address_space(3))) u32*)l, 16, 0, 0);
}

// ---------------------------------------------------------------------------
// zero the padded-image border cells (68 cells/sample x 512 c)
// ---------------------------------------------------------------------------
__global__ __launch_bounds__(256) void zero_borders(u16* __restrict__ pad) {
    const int n = blockIdx.x, t = threadIdx.x;
    short8 z = (short8){0,0,0,0,0,0,0,0};
    for (int idx = t; idx < 68 * 64; idx += 256) {
        int cell = idx >> 6, ch = idx & 63;
        int hh, ww;
        if (cell < 18)      { hh = 0;          ww = cell; }
        else if (cell < 36) { hh = 17;         ww = cell - 18; }
        else if (cell < 52) { hh = cell - 35;  ww = 0; }
        else                { hh = cell - 51;  ww = 17; }
        *(short8*)(pad + ((size_t)((n * 18 + hh) * 18 + ww)) * 512 + ch * 8) = z;
    }
}

// ---------------------------------------------------------------------------
// NCHW fp32 -> padded pixel-major bf16 [n][18][18][512] (interior only)
// ---------------------------------------------------------------------------
__global__ __launch_bounds__(256) void prep_x(const float* __restrict__ x, u16* __restrict__ pad) {
    __shared__ float tl[64][65];
    const int n = blockIdx.z, c0 = blockIdx.y * 64, p0 = blockIdx.x * 64;
    const int t = threadIdx.x;
    {
        const int cc = t >> 2, ps = (t & 3) * 16;
#pragma unroll
        for (int i = 0; i < 4; ++i) {
            float4 v4 = *(const float4*)(x + (((size_t)(n * 512 + c0 + cc)) << 8) + p0 + ps + i * 4);
            tl[cc][ps + i * 4 + 0] = v4.x;
            tl[cc][ps + i * 4 + 1] = v4.y;
            tl[cc][ps + i * 4 + 2] = v4.z;
            tl[cc][ps + i * 4 + 3] = v4.w;
        }
    }
    __syncthreads();
    {
        const int pp = t >> 2, cs = (t & 3) * 16;
        short8 o0, o1;
#pragma unroll
        for (int i = 0; i < 8; ++i) o0[i] = (short)f2bf(tl[cs + i][pp]);
#pragma unroll
        for (int i = 0; i < 8; ++i) o1[i] = (short)f2bf(tl[cs + 8 + i][pp]);
        const int p = p0 + pp, h = p >> 4, wcol = p & 15;
        u16* dst = pad + ((size_t)((n * 18 + h + 1) * 18 + wcol + 1)) * 512 + c0 + cs;
        *(short8*)(dst + 0) = o0;
        *(short8*)(dst + 8) = o1;
    }
}

// ---------------------------------------------------------------------------
// weights fp32 [co][ci][3][3] -> bf16 Wt[sel][tap][co][ci]
// ---------------------------------------------------------------------------
__global__ __launch_bounds__(256) void prep_w(
    const float* __restrict__ Wq, const float* __restrict__ Wk,
    const float* __restrict__ Wv, const float* __restrict__ Wc,
    u16* __restrict__ Wt)
{
    __shared__ float lw[4608];
    const int co = blockIdx.x, sel = blockIdx.y, t = threadIdx.x;
    const float* Ws = (sel == 0) ? Wq : (sel == 1) ? Wk : (sel == 2) ? Wv : Wc;
#pragma unroll
    for (int i = 0; i < 18; ++i) lw[t + i * 256] = Ws[(size_t)co * 4608 + t + i * 256];
    __syncthreads();
    for (int tap = 0; tap < 9; ++tap)
#pragma unroll
        for (int hh = 0; hh < 2; ++hh) {
            int ci = t + hh * 256;
            Wt[(((size_t)(sel * 9 + tap)) << 18) + (co << 9) + ci] = f2bf(lw[ci * 9 + tap]);
        }
}

// ---------------------------------------------------------------------------
// Fused QKV conv3x3 implicit GEMM: M=16384 imrows (p-major), N=1536 (q|k|v co),
// K=4608 (9 taps x 512). BM=256, BN=192, BK=32. 512 thr = 8 waves (2M x 4N).
// Triple-buffered LDS; ONE barrier + ONE counted vmcnt per K-tile:
//   top-of-kt:  vmcnt(4) [kt's stages landed, kt+1's may fly] -> s_barrier
//   body:       11 ds_read frags | issue stages for kt+2 | 24 MFMA
// LDS rotation swizzle (bank-group = 4*(row&1)+chunk mod 8):
//   read:  phys_chunk = (logical + (row>>1)) & 3
//   stage: lane fetches logical = ((l&3) - (l>>3)) & 3  (linear LDS dest)
// ---------------------------------------------------------------------------
__global__ __launch_bounds__(512, 1) void qkv_mfma8(
    const u16* __restrict__ pad, const u16* __restrict__ Wt,
    u16* __restrict__ q, u16* __restrict__ k, u16* __restrict__ v)
{
    __shared__ short As[3][8192];   // [256 rows][32 k] per buf, 16KB
    __shared__ short Bs[3][6144];   // [192 rows][32 k] per buf, 12KB
    const int t = threadIdx.x;
    const int l = t & 63;
    const int wid = t >> 6;
    const int wm = wid >> 2, wn = wid & 3;

    // XCD-bijective block swizzle (512 blocks, 8 XCDs)
    const int o = blockIdx.x;
    const int wg = (o & 7) * 64 + (o >> 3);
    const int imbase = (wg >> 3) * 256;
    const int cobase = (wg & 7) * 192;

    // ---- staging: wave unit = 16 rows x 64B; lane l -> row l>>2, phys chunk l&3.
    // logical chunk fetched = ((l&3) - (row>>1)) & 3, (row>>1)&3 == (l>>3)&3.
    const int cl = ((l & 3) - ((l >> 3) & 3)) & 3;
    int imoffA[2], woffB[2];
#pragma unroll
    for (int rr = 0; rr < 2; ++rr) {
        const int chunk = wid * 2 + rr;
        const int imrow = imbase + chunk * 16 + (l >> 2);
        const int p = imrow >> 6, n = imrow & 63;
        imoffA[rr] = ((n * 18 + (p >> 4)) * 18 + (p & 15)) * 512 + cl * 8;
        const int cof = cobase + chunk * 16 + (l >> 2);
        const int sel = cof >> 9, co = cof & 511;
        woffB[rr] = sel * 9 * 262144 + co * 512 + cl * 8;   // only used if wid<6
    }

    // ---- fragment read offsets: row = base16 + (l&15), logical chunk = l>>4,
    // phys = (logical + (row>>1)) & 3, (row>>1)&3 == (l>>1)&3.
    const int fp = ((l >> 4) + (l >> 1)) & 3;
    const int aoff = (wm * 128 + (l & 15)) * 32 + fp * 8;
    const int boff = (wn * 48 + (l & 15)) * 32 + fp * 8;

    f32x4 acc[8][3];
#pragma unroll
    for (int i = 0; i < 8; ++i)
#pragma unroll
        for (int j = 0; j < 3; ++j) acc[i][j] = (f32x4){0.f, 0.f, 0.f, 0.f};

    auto STAGE_A = [&](int kt, int s) {
        const int tap = kt >> 4;
        const int shift = ((tap / 3) * 18 + (tap % 3)) * 512 + (kt & 15) * 32;
#pragma unroll
        for (int rr = 0; rr < 2; ++rr)
            gload_lds16(pad + imoffA[rr] + shift, (u16*)(&As[s][0] + (wid * 2 + rr) * 512));
    };
    auto STAGE_B = [&](int kt, int s) {
        if (wid < 6) {
            const int tap = kt >> 4;
            const int shift = tap * 262144 + (kt & 15) * 32;
#pragma unroll
            for (int rr = 0; rr < 2; ++rr)
                gload_lds16(Wt + woffB[rr] + shift, (u16*)(&Bs[s][0] + (wid * 2 + rr) * 512));
        }
    };

    // prologue: stage kt=0 and kt=1
    STAGE_A(0, 0); STAGE_B(0, 0);
    STAGE_A(1, 1); STAGE_B(1, 1);

    int s0 = 0;
    short8 fa0[4], fa1[4], fb[3];
#pragma unroll 1
    for (int kt = 0; kt < 144; ++kt) {
        const int s2 = (s0 == 0) ? 2 : s0 - 1;    // (kt+2)%3
        const short* Ab = &As[s0][0];
        const short* Bb = &Bs[s0][0];

        // ---- top-of-kt: kt's stages must be landed for ALL waves before any
        // wave reads them -> counted vmcnt BEFORE the barrier.
        if (kt == 143) {
            asm volatile("s_waitcnt vmcnt(0)" ::: "memory");
        } else if (wid < 6) {
            asm volatile("s_waitcnt vmcnt(4)" ::: "memory");
        } else {
            asm volatile("s_waitcnt vmcnt(2)" ::: "memory");
        }
        __builtin_amdgcn_sched_barrier(0);
        __builtin_amdgcn_s_barrier();
        __builtin_amdgcn_sched_barrier(0);

        // ---- fragment reads (compiler inserts fine-grained lgkmcnt)
#pragma unroll
        for (int j = 0; j < 3; ++j) fb[j] = *(const short8*)(Bb + boff + j * 512);
#pragma unroll
        for (int i = 0; i < 4; ++i) fa0[i] = *(const short8*)(Ab + aoff + i * 512);
#pragma unroll
        for (int i = 0; i < 4; ++i) fa1[i] = *(const short8*)(Ab + aoff + 2048 + i * 512);

        // ---- issue stages for kt+2 into the buffer freed at this barrier
        if (kt < 142) { STAGE_A(kt + 2, s2); STAGE_B(kt + 2, s2); }

        __builtin_amdgcn_s_setprio(1);
#pragma unroll
        for (int i = 0; i < 4; ++i)
#pragma unroll
            for (int j = 0; j < 3; ++j)
                acc[i][j] = __builtin_amdgcn_mfma_f32_16x16x32_bf16(fa0[i], fb[j], acc[i][j], 0, 0, 0);
#pragma unroll
        for (int i = 0; i < 4; ++i)
#pragma unroll
            for (int j = 0; j < 3; ++j)
                acc[4 + i][j] = __builtin_amdgcn_mfma_f32_16x16x32_bf16(fa1[i], fb[j], acc[4 + i][j], 0, 0, 0);
        __builtin_amdgcn_s_setprio(0);

        s0 = (s0 == 2) ? 0 : s0 + 1;
    }

    // epilogue: C layout col = lane&15, row = (lane>>4)*4 + reg
#pragma unroll
    for (int j = 0; j < 3; ++j) {
        const int colb = cobase + wn * 48 + j * 16;
        u16* op = ((colb >> 9) == 0) ? q : (((colb >> 9) == 1) ? k : v);
        op += (colb & 511) + (l & 15);
#pragma unroll
        for (int i = 0; i < 8; ++i) {
            const int row = imbase + wm * 128 + i * 16 + (l >> 4) * 4;
#pragma unroll
            for (int r = 0; r < 4; ++r)
                op[(size_t)(row + r) * 512] = f2bf(acc[i][j][r]);
        }
    }
}

// ---------------------------------------------------------------------------
// final conv3x3 + residual (128x128 2-phase structure, rotation swizzle)
// M=co, N=im-rows (n-major); out NCHW fp32 + residual. grid (x=128, y=4)
// ---------------------------------------------------------------------------
__global__ __launch_bounds__(256, 2) void cres_mfma(
    const u16* __restrict__ pad, const u16* __restrict__ Wt,
    const float* __restrict__ xres, float* __restrict__ out)
{
    __shared__ short bufA[2][4096];
    __shared__ short bufB[2][4096];
    const int t = threadIdx.x;
    const int l = t & 63;
    const int w = t >> 6;
    const int wr = w >> 1, wc = w & 1;

    const int imbase = blockIdx.x * 128;
    const int cobase = blockIdx.y * 128;

    const int lr = l >> 2;
    const int cl = ((l & 3) - ((l >> 3) & 3)) & 3;   // rotation swizzle, staging side
    int imoff[2], woff[2];
#pragma unroll
    for (int i = 0; i < 2; ++i) {
        int r = w * 32 + i * 16 + lr;
        int imrow = imbase + r;
        int n = imrow >> 8, p = imrow & 255;
        int h = p >> 4, wco = p & 15;
        imoff[i] = ((n * 18 + h) * 18 + wco) * 512 + cl * 8;
        woff[i]  = (cobase + r) * 512 + cl * 8;
    }
    const int fragoff = (l & 15) * 32 + ((((l >> 4) + (l >> 1)) & 3)) * 8;

    f32x4 acc[4][4];
#pragma unroll
    for (int a = 0; a < 4; ++a)
#pragma unroll
        for (int b = 0; b < 4; ++b) acc[a][b] = (f32x4){0.f, 0.f, 0.f, 0.f};

    auto STAGE = [&](int s, int j, int k0) {
        const int shift = ((j / 3) * 18 + (j % 3)) * 512 + k0;
        const size_t wjo = ((size_t)j << 18) + k0;
#pragma unroll
        for (int i = 0; i < 2; ++i) {
            gload_lds16(pad + imoff[i] + shift, (u16*)&bufA[s][(w * 32 + i * 16) * 32]);
            gload_lds16(Wt + woff[i]  + wjo,   (u16*)&bufB[s][(w * 32 + i * 16) * 32]);
        }
    };

    STAGE(0, 0, 0);
    __syncthreads();

    for (int kt = 0; kt < 144; ++kt) {
        const int cur = kt & 1;
        if (kt < 143) {
            const int kn = kt + 1;
            STAGE(cur ^ 1, kn >> 4, (kn & 15) * 32);
        }
        short8 fa[4], fb[4];
        const short* IMb = &bufA[cur][0];
        const short* Wb  = &bufB[cur][0];
#pragma unroll
        for (int f = 0; f < 4; ++f) {
            const int imr = wc * 64 + f * 16;
            const int wrr = wr * 64 + f * 16;
            fb[f] = *(const short8*)(IMb + imr * 32 + fragoff);
            fa[f] = *(const short8*)(Wb  + wrr * 32 + fragoff);
        }
#pragma unroll
        for (int fm = 0; fm < 4; ++fm)
#pragma unroll
            for (int fn = 0; fn < 4; ++fn)
                acc[fm][fn] = __builtin_amdgcn_mfma_f32_16x16x32_bf16(fa[fm], fb[fn], acc[fm][fn], 0, 0, 0);
        __syncthreads();
    }

#pragma unroll
    for (int fm = 0; fm < 4; ++fm)
#pragma unroll
        for (int fn = 0; fn < 4; ++fn)
#pragma unroll
            for (int r = 0; r < 4; ++r) {
                int co = cobase + wr * 64 + fm * 16 + (l >> 4) * 4 + r;
                int imrow = imbase + wc * 64 + fn * 16 + (l & 15);
                int n = imrow >> 8, p = imrow & 255;
                size_t addr = (((size_t)(n * 512 + co)) << 8) + p;
                out[addr] = acc[fm][fn][r] + xres[addr];
            }
}

// ---------------------------------------------------------------------------
// attention per pixel (bf16 in, bf16 out in place of v)
// ---------------------------------------------------------------------------
__global__ __launch_bounds__(256) void attn_kernel(
    const u16* __restrict__ qT, const u16* __restrict__ kT, u16* vvT)
{
    const int p = blockIdx.x;
    const int t = threadIdx.x;
    __shared__ float smemA[2][64][68];
    __shared__ float attb[64][68];
    const size_t pb = (size_t)p * (NB * CCH);

    const int ng = t >> 4, mg = t & 15;
    const int n0 = ng * 4, m0 = mg * 4;
    float acc[4][4];
#pragma unroll
    for (int i = 0; i < 4; ++i)
#pragma unroll
        for (int j = 0; j < 4; ++j) acc[i][j] = 0.f;

    for (int ct = 0; ct < 8; ++ct) {
        const int c0 = ct * 64;
        __syncthreads();
#pragma unroll
        for (int s = 0; s < 2; ++s) {
            int f = t + s * 256;
            int nn = f >> 3, c8 = (f & 7) * 8;
            short8 qv = *(const short8*)(qT + pb + (size_t)nn * CCH + c0 + c8);
            short8 kv = *(const short8*)(kT + pb + (size_t)nn * CCH + c0 + c8);
#pragma unroll
            for (int e = 0; e < 8; ++e) {
                smemA[0][nn][c8 + e] = bf2f((u16)qv[e]);
                smemA[1][nn][c8 + e] = bf2f((u16)kv[e]);
            }
        }
        __syncthreads();
#pragma unroll 4
        for (int c4 = 0; c4 < 16; ++c4) {
            float4 q4[4], k4[4];
#pragma unroll
            for (int i = 0; i < 4; ++i) q4[i] = *(const float4*)&smemA[0][n0 + i][c4 * 4];
#pragma unroll
            for (int j = 0; j < 4; ++j) k4[j] = *(const float4*)&smemA[1][m0 + j][c4 * 4];
#pragma unroll
            for (int i = 0; i < 4; ++i)
#pragma unroll
                for (int j = 0; j < 4; ++j) {
                    acc[i][j] = fmaf(q4[i].x, k4[j].x, acc[i][j]);
                    acc[i][j] = fmaf(q4[i].y, k4[j].y, acc[i][j]);
                    acc[i][j] = fmaf(q4[i].z, k4[j].z, acc[i][j]);
                    acc[i][j] = fmaf(q4[i].w, k4[j].w, acc[i][j]);
                }
        }
    }

    const float SCALE = 0.0441941738241592f;  // 1/sqrt(512)
#pragma unroll
    for (int i = 0; i < 4; ++i) {
        float m = fmaxf(fmaxf(acc[i][0], acc[i][1]), fmaxf(acc[i][2], acc[i][3]));
#pragma unroll
        for (int mask = 1; mask < 16; mask <<= 1) m = fmaxf(m, __shfl_xor(m, mask, 16));
        float e[4]; float s = 0.f;
#pragma unroll
        for (int j = 0; j < 4; ++j) { e[j] = __expf((acc[i][j] - m) * SCALE); s += e[j]; }
#pragma unroll
        for (int mask = 1; mask < 16; mask <<= 1) s += __shfl_xor(s, mask, 16);
        float inv = 1.f / s;
#pragma unroll
        for (int j = 0; j < 4; ++j) attb[n0 + i][m0 + j] = e[j] * inv;
    }
    __syncthreads();

    float* vs = &smemA[0][0][0];  // vs[m*132 + c]
    const int ng2 = t >> 3, cg = t & 7;
    const int nn0 = ng2 * 2, cb = cg * 16;
    for (int ct4 = 0; ct4 < 4; ++ct4) {
        const int c0 = ct4 * 128;
#pragma unroll
        for (int s = 0; s < 4; ++s) {
            int f = t + s * 256;
            int m = f >> 4, c8 = (f & 15) * 8;
            short8 vv = *(const short8*)(vvT + pb + (size_t)m * CCH + c0 + c8);
#pragma unroll
            for (int e = 0; e < 8; ++e) vs[m * 132 + c8 + e] = bf2f((u16)vv[e]);
        }
        __syncthreads();
        float acc2[2][16];
#pragma unroll
        for (int i = 0; i < 2; ++i)
#pragma unroll
            for (int j = 0; j < 16; ++j) acc2[i][j] = 0.f;
#pragma unroll 4
        for (int m = 0; m < 64; ++m) {
            float a0 = attb[nn0][m], a1 = attb[nn0 + 1][m];
#pragma unroll
            for (int k4 = 0; k4 < 4; ++k4) {
                float4 v4 = *(const float4*)&vs[m * 132 + cb + k4 * 4];
                acc2[0][k4 * 4 + 0] = fmaf(a0, v4.x, acc2[0][k4 * 4 + 0]);
                acc2[0][k4 * 4 + 1] = fmaf(a0, v4.y, acc2[0][k4 * 4 + 1]);
                acc2[0][k4 * 4 + 2] = fmaf(a0, v4.z, acc2[0][k4 * 4 + 2]);
                acc2[0][k4 * 4 + 3] = fmaf(a0, v4.w, acc2[0][k4 * 4 + 3]);
                acc2[1][k4 * 4 + 0] = fmaf(a1, v4.x, acc2[1][k4 * 4 + 0]);
                acc2[1][k4 * 4 + 1] = fmaf(a1, v4.y, acc2[1][k4 * 4 + 1]);
                acc2[1][k4 * 4 + 2] = fmaf(a1, v4.z, acc2[1][k4 * 4 + 2]);
                acc2[1][k4 * 4 + 3] = fmaf(a1, v4.w, acc2[1][k4 * 4 + 3]);
            }
        }
#pragma unroll
        for (int i = 0; i < 2; ++i)
#pragma unroll
            for (int j = 0; j < 16; ++j)
                vvT[pb + (size_t)(nn0 + i) * CCH + c0 + cb + j] = f2bf(acc2[i][j]);
        __syncthreads();
    }
}

// ---------------------------------------------------------------------------
// GroupNorm(1,C)+affine+ReLU: virt bf16 [p][n][c] -> ypad bf16 [n][18][18][c]
// ---------------------------------------------------------------------------
__global__ __launch_bounds__(256) void gn_kernel(
    const u16* __restrict__ virtT, const float* __restrict__ gamma,
    const float* __restrict__ beta, u16* __restrict__ ypad)
{
    const int n = blockIdx.x, t = threadIdx.x;
    __shared__ float sg[512], sb[512];
    for (int i = t; i < 512; i += 256) { sg[i] = gamma[i]; sb[i] = beta[i]; }

    float sum = 0.f, ss = 0.f;
    for (int it = 0; it < 64; ++it) {
        int f = t + it * 256;
        int p = f >> 6, c = (f & 63) * 8;
        short8 vv = *(const short8*)(virtT + ((size_t)(p * 64 + n)) * 512 + c);
#pragma unroll
        for (int e = 0; e < 8; ++e) { float x = bf2f((u16)vv[e]); sum += x; ss = fmaf(x, x, ss); }
    }
#pragma unroll
    for (int off = 32; off > 0; off >>= 1) {
        sum += __shfl_down(sum, off);
        ss  += __shfl_down(ss, off);
    }
    __shared__ float rs[4], rss[4], stats[2];
    const int wid = t >> 6, lane = t & 63;
    if (lane == 0) { rs[wid] = sum; rss[wid] = ss; }
    __syncthreads();
    if (t == 0) {
        float S = rs[0] + rs[1] + rs[2] + rs[3];
        float SS = rss[0] + rss[1] + rss[2] + rss[3];
        float mu = S * (1.f / 131072.f);
        float var = SS * (1.f / 131072.f) - mu * mu;
        stats[0] = mu;
        stats[1] = rsqrtf(var + 1e-5f);
    }
    __syncthreads();
    const float mu = stats[0], rstd = stats[1];

    for (int it = 0; it < 64; ++it) {
        int f = t + it * 256;
        int p = f >> 6, cc = (f & 63) * 8;
        short8 vv = *(const short8*)(virtT + ((size_t)(p * 64 + n)) * 512 + cc);
        short8 ov;
#pragma unroll
        for (int e = 0; e < 8; ++e) {
            float x = (bf2f((u16)vv[e]) - mu) * rstd;
            x = fmaf(x, sg[cc + e], sb[cc + e]);
            ov[e] = (short)f2bf(fmaxf(x, 0.f));
        }
        int h = p >> 4, wcol = p & 15;
        *(short8*)(ypad + ((size_t)((n * 18 + h + 1) * 18 + wcol + 1)) * 512 + cc) = ov;
    }
}

// ---------------------------------------------------------------------------
extern "C" void kernel_launch(void* const* d_in, const int* in_sizes, int n_in,
                              void* d_out, int out_size, void* d_ws, size_t ws_size,
                              hipStream_t stream)
{
    const float* x     = (const float*)d_in[0];
    const float* Wq    = (const float*)d_in[1];
    const float* Wk    = (const float*)d_in[2];
    const float* Wv    = (const float*)d_in[3];
    const float* Wc    = (const float*)d_in[4];
    const float* gamma = (const float*)d_in[5];
    const float* beta  = (const float*)d_in[6];
    float* out = (float*)d_out;

    // workspace (u16 units): pad | Wt | q | k | v  (~90.4 MB total)
    u16* pad = (u16*)d_ws;
    u16* Wt  = pad + 10616832;
    u16* q   = Wt + 9437184;
    u16* k   = q + 8388608;
    u16* v   = k + 8388608;   // virt written in place after PV

    zero_borders<<<dim3(64), dim3(256), 0, stream>>>(pad);
    prep_x<<<dim3(4, 8, 64), dim3(256), 0, stream>>>(x, pad);
    prep_w<<<dim3(512, 4), dim3(256), 0, stream>>>(Wq, Wk, Wv, Wc, Wt);

    qkv_mfma8<<<dim3(512), dim3(512), 0, stream>>>(pad, Wt, q, k, v);
    attn_kernel<<<dim3(256), dim3(256), 0, stream>>>(q, k, v);
    gn_kernel<<<dim3(64), dim3(256), 0, stream>>>(v, gamma, beta, pad);
    cres_mfma<<<dim3(128, 4), dim3(256), 0, stream>>>(pad, Wt + 3 * 2359296, x, out);
}

// Round 5
// 399.027 us; speedup vs baseline: 11.4914x; 1.0721x over previous
//
#include <hip/hip_runtime.h>
#include <math.h>

typedef unsigned short u16;
typedef unsigned int u32;
typedef short short8 __attribute__((ext_vector_type(8)));
typedef float f32x4 __attribute__((ext_vector_type(4)));

#define NB 64
#define CCH 512
#define HW 256

// ---- bf16 helpers (bit-level, RNE) ----
__device__ __forceinline__ u16 f2bf(float f) {
    union { float f; u32 u; } x; x.f = f;
    u32 r = x.u + 0x7fffu + ((x.u >> 16) & 1u);
    return (u16)(r >> 16);
}
__device__ __forceinline__ float bf2f(u16 b) {
    union { u32 u; float f; } x; x.u = ((u32)b) << 16;
    return x.f;
}
__device__ __forceinline__ void gload_lds16(const u16* g, u16* l) {
    __builtin_amdgcn_global_load_lds((const __attribute__((address_space(1))) u32*)g,
                                     (__attribute__((address_space(3))) u32*)l, 16, 0, 0);
}

// ---------------------------------------------------------------------------
__global__ __launch_bounds__(256) void zero_borders(u16* __restrict__ pad) {
    const int n = blockIdx.x, t = threadIdx.x;
    short8 z = (short8){0,0,0,0,0,0,0,0};
    for (int idx = t; idx < 68 * 64; idx += 256) {
        int cell = idx >> 6, ch = idx & 63;
        int hh, ww;
        if (cell < 18)      { hh = 0;          ww = cell; }
        else if (cell < 36) { hh = 17;         ww = cell - 18; }
        else if (cell < 52) { hh = cell - 35;  ww = 0; }
        else                { hh = cell - 51;  ww = 17; }
        *(short8*)(pad + ((size_t)((n * 18 + hh) * 18 + ww)) * 512 + ch * 8) = z;
    }
}

// ---------------------------------------------------------------------------
// NCHW fp32 -> padded pixel-major bf16 [n][18][18][512] (interior only)
// ---------------------------------------------------------------------------
__global__ __launch_bounds__(256) void prep_x(const float* __restrict__ x, u16* __restrict__ pad) {
    __shared__ float tl[64][65];
    const int n = blockIdx.z, c0 = blockIdx.y * 64, p0 = blockIdx.x * 64;
    const int t = threadIdx.x;
    {
        const int cc = t >> 2, ps = (t & 3) * 16;
#pragma unroll
        for (int i = 0; i < 4; ++i) {
            float4 v4 = *(const float4*)(x + (((size_t)(n * 512 + c0 + cc)) << 8) + p0 + ps + i * 4);
            tl[cc][ps + i * 4 + 0] = v4.x;
            tl[cc][ps + i * 4 + 1] = v4.y;
            tl[cc][ps + i * 4 + 2] = v4.z;
            tl[cc][ps + i * 4 + 3] = v4.w;
        }
    }
    __syncthreads();
    {
        const int pp = t >> 2, cs = (t & 3) * 16;
        short8 o0, o1;
#pragma unroll
        for (int i = 0; i < 8; ++i) o0[i] = (short)f2bf(tl[cs + i][pp]);
#pragma unroll
        for (int i = 0; i < 8; ++i) o1[i] = (short)f2bf(tl[cs + 8 + i][pp]);
        const int p = p0 + pp, h = p >> 4, wcol = p & 15;
        u16* dst = pad + ((size_t)((n * 18 + h + 1) * 18 + wcol + 1)) * 512 + c0 + cs;
        *(short8*)(dst + 0) = o0;
        *(short8*)(dst + 8) = o1;
    }
}

// ---------------------------------------------------------------------------
// weights fp32 [co][ci][3][3] -> bf16 Wt[sel][tap][co][ci]
// ---------------------------------------------------------------------------
__global__ __launch_bounds__(256) void prep_w(
    const float* __restrict__ Wq, const float* __restrict__ Wk,
    const float* __restrict__ Wv, const float* __restrict__ Wc,
    u16* __restrict__ Wt)
{
    __shared__ float lw[4608];
    const int co = blockIdx.x, sel = blockIdx.y, t = threadIdx.x;
    const float* Ws = (sel == 0) ? Wq : (sel == 1) ? Wk : (sel == 2) ? Wv : Wc;
#pragma unroll
    for (int i = 0; i < 18; ++i) lw[t + i * 256] = Ws[(size_t)co * 4608 + t + i * 256];
    __syncthreads();
    for (int tap = 0; tap < 9; ++tap)
#pragma unroll
        for (int hh = 0; hh < 2; ++hh) {
            int ci = t + hh * 256;
            Wt[(((size_t)(sel * 9 + tap)) << 18) + (co << 9) + ci] = f2bf(lw[ci * 9 + tap]);
        }
}

// ---------------------------------------------------------------------------
// Fused QKV conv3x3 implicit GEMM, quad-buffered register-pipelined K-loop.
// M=16384 imrows (p-major), N=1536 (q|k|v co), K=4608. BM=256, BN=192, BK=32.
// 8 waves (2M x 4N), wave tile 128x48.
// Pipeline: at tile kt, MFMA frags(kt) [read during kt-1] while reading
// frags(kt+1) from LDS buf (kt+1)&3 and staging tile kt+3 into buf (kt+3)&3.
// Top-of-tile: counted vmcnt (own kt+1-batch landed) + barrier. Never drains.
// Rotation swizzle (verified r4, zero conflicts): stage cl=((l&3)-(l>>3))&3,
// frag phys chunk = ((l>>4)+(l>>1))&3.
// ---------------------------------------------------------------------------
__global__ __launch_bounds__(512, 1) void qkv_mfma8(
    const u16* __restrict__ pad, const u16* __restrict__ Wt,
    u16* __restrict__ q, u16* __restrict__ k, u16* __restrict__ v)
{
    __shared__ short As[4][8192];   // 4 x 16KB
    __shared__ short Bs[4][6144];   // 4 x 12KB
    const int t = threadIdx.x;
    const int l = t & 63;
    const int wid = t >> 6;
    const int wm = wid >> 2, wn = wid & 3;

    // XCD-bijective block swizzle (512 blocks, 8 XCDs)
    const int o = blockIdx.x;
    const int wg = (o & 7) * 64 + (o >> 3);
    const int imbase = (wg >> 3) * 256;
    const int cobase = (wg & 7) * 192;

    const int cl = ((l & 3) - ((l >> 3) & 3)) & 3;
    int imoffA[2], woffB[2];
#pragma unroll
    for (int rr = 0; rr < 2; ++rr) {
        const int chunk = wid * 2 + rr;
        const int imrow = imbase + chunk * 16 + (l >> 2);
        const int p = imrow >> 6, n = imrow & 63;
        imoffA[rr] = ((n * 18 + (p >> 4)) * 18 + (p & 15)) * 512 + cl * 8;
        const int cof = cobase + chunk * 16 + (l >> 2);
        const int sel = cof >> 9, co = cof & 511;
        woffB[rr] = sel * 9 * 262144 + co * 512 + cl * 8;   // used if wid<6
    }

    const int fp = ((l >> 4) + (l >> 1)) & 3;
    const int aoff = (wm * 128 + (l & 15)) * 32 + fp * 8;
    const int boff = (wn * 48 + (l & 15)) * 32 + fp * 8;

    f32x4 acc[8][3];
#pragma unroll
    for (int i = 0; i < 8; ++i)
#pragma unroll
        for (int j = 0; j < 3; ++j) acc[i][j] = (f32x4){0.f, 0.f, 0.f, 0.f};

    auto STAGE_A = [&](int kt, int s) {
        const int tap = kt >> 4;
        const int shift = ((tap / 3) * 18 + (tap % 3)) * 512 + (kt & 15) * 32;
#pragma unroll
        for (int rr = 0; rr < 2; ++rr)
            gload_lds16(pad + imoffA[rr] + shift, (u16*)(&As[s][0] + (wid * 2 + rr) * 512));
    };
    auto STAGE_B = [&](int kt, int s) {
        if (wid < 6) {
            const int tap = kt >> 4;
            const int shift = tap * 262144 + (kt & 15) * 32;
#pragma unroll
            for (int rr = 0; rr < 2; ++rr)
                gload_lds16(Wt + woffB[rr] + shift, (u16*)(&Bs[s][0] + (wid * 2 + rr) * 512));
        }
    };

    // prologue: stage tiles 0,1,2
    STAGE_A(0, 0); STAGE_B(0, 0);
    STAGE_A(1, 1); STAGE_B(1, 1);
    STAGE_A(2, 2); STAGE_B(2, 2);
    if (wid < 6) asm volatile("s_waitcnt vmcnt(8)" ::: "memory");
    else         asm volatile("s_waitcnt vmcnt(4)" ::: "memory");
    __builtin_amdgcn_sched_barrier(0);
    __builtin_amdgcn_s_barrier();
    __builtin_amdgcn_sched_barrier(0);

    short8 A0[8], A1[8], B0[3], B1[3];
    // pre-read frags(0) into set0
#pragma unroll
    for (int j = 0; j < 3; ++j) B0[j] = *(const short8*)(&Bs[0][0] + boff + j * 512);
#pragma unroll
    for (int i = 0; i < 8; ++i) A0[i] = *(const short8*)(&As[0][0] + aoff + i * 512);

#define QSTEP(KT, BUFR, BUFS, AM, BMF, AR, BRF)                                   \
    {                                                                             \
        if ((KT) >= 142)  asm volatile("s_waitcnt vmcnt(0)" ::: "memory");        \
        else if (wid < 6) asm volatile("s_waitcnt vmcnt(4)" ::: "memory");        \
        else              asm volatile("s_waitcnt vmcnt(2)" ::: "memory");        \
        __builtin_amdgcn_sched_barrier(0);                                        \
        __builtin_amdgcn_s_barrier();                                             \
        __builtin_amdgcn_sched_barrier(0);                                        \
        if ((KT) < 143) {                                                         \
            const short* Abr = &As[BUFR][0];                                      \
            const short* Bbr = &Bs[BUFR][0];                                      \
            _Pragma("unroll")                                                     \
            for (int j = 0; j < 3; ++j) BRF[j] = *(const short8*)(Bbr + boff + j * 512); \
            _Pragma("unroll")                                                     \
            for (int i = 0; i < 8; ++i) AR[i] = *(const short8*)(Abr + aoff + i * 512);  \
        }                                                                         \
        if ((KT) + 3 < 144) { STAGE_A((KT) + 3, BUFS); STAGE_B((KT) + 3, BUFS); } \
        __builtin_amdgcn_s_setprio(1);                                            \
        _Pragma("unroll")                                                         \
        for (int i = 0; i < 8; ++i)                                               \
            _Pragma("unroll")                                                     \
            for (int j = 0; j < 3; ++j)                                           \
                acc[i][j] = __builtin_amdgcn_mfma_f32_16x16x32_bf16(AM[i], BMF[j], acc[i][j], 0, 0, 0); \
        __builtin_amdgcn_s_setprio(0);                                            \
    }

#pragma unroll 1
    for (int kt = 0; kt < 144; kt += 4) {
        QSTEP(kt + 0, 1, 3, A0, B0, A1, B1);
        QSTEP(kt + 1, 2, 0, A1, B1, A0, B0);
        QSTEP(kt + 2, 3, 1, A0, B0, A1, B1);
        QSTEP(kt + 3, 0, 2, A1, B1, A0, B0);
    }
#undef QSTEP

    // epilogue: C layout col = lane&15, row = (lane>>4)*4 + reg
#pragma unroll
    for (int j = 0; j < 3; ++j) {
        const int colb = cobase + wn * 48 + j * 16;
        u16* op = ((colb >> 9) == 0) ? q : (((colb >> 9) == 1) ? k : v);
        op += (colb & 511) + (l & 15);
#pragma unroll
        for (int i = 0; i < 8; ++i) {
            const int row = imbase + wm * 128 + i * 16 + (l >> 4) * 4;
#pragma unroll
            for (int r = 0; r < 4; ++r)
                op[(size_t)(row + r) * 512] = f2bf(acc[i][j][r]);
        }
    }
}

// ---------------------------------------------------------------------------
// Final conv3x3 + residual, same quad-buffered pipelined structure.
// A = Wc (M=co, BM=128), B = image rows n-major (N=16384, BN=256), BK=32.
// 8 waves 2M x 4N, wave tile 64x64 (4x4 frags). 256 blocks = 1 round/CU.
// Per-wave stage batch = 1 A-unit + 2 B-units = 3 gloads (uniform).
// ---------------------------------------------------------------------------
__global__ __launch_bounds__(512, 1) void cres_pipe(
    const u16* __restrict__ pad, const u16* __restrict__ WtC,
    const float* __restrict__ xres, float* __restrict__ out)
{
    __shared__ short As[4][4096];   // 4 x 8KB  (128 co x 32)
    __shared__ short Bs[4][8192];   // 4 x 16KB (256 imrows x 32)
    const int t = threadIdx.x;
    const int l = t & 63;
    const int wid = t >> 6;
    const int wm = wid >> 2, wn = wid & 3;

    const int cobase = (blockIdx.x & 3) * 128;
    const int imbase = (blockIdx.x >> 2) * 256;   // == sample n*256

    const int cl = ((l & 3) - ((l >> 3) & 3)) & 3;
    int woffA, imoffB[2];
    {
        const int co = cobase + wid * 16 + (l >> 2);
        woffA = co * 512 + cl * 8;
    }
#pragma unroll
    for (int rr = 0; rr < 2; ++rr) {
        const int u = wid * 2 + rr;
        const int imrow = imbase + u * 16 + (l >> 2);
        const int n = imrow >> 8, p = imrow & 255;
        imoffB[rr] = ((n * 18 + (p >> 4)) * 18 + (p & 15)) * 512 + cl * 8;
    }

    const int fp = ((l >> 4) + (l >> 1)) & 3;
    const int aoff = (wm * 64 + (l & 15)) * 32 + fp * 8;
    const int boff = (wn * 64 + (l & 15)) * 32 + fp * 8;

    f32x4 acc[4][4];
#pragma unroll
    for (int i = 0; i < 4; ++i)
#pragma unroll
        for (int j = 0; j < 4; ++j) acc[i][j] = (f32x4){0.f, 0.f, 0.f, 0.f};

    auto STAGE_CA = [&](int kt, int s) {
        const int tap = kt >> 4;
        const int shift = tap * 262144 + (kt & 15) * 32;
        gload_lds16(WtC + woffA + shift, (u16*)(&As[s][0] + wid * 512));
    };
    auto STAGE_CB = [&](int kt, int s) {
        const int tap = kt >> 4;
        const int shift = ((tap / 3) * 18 + (tap % 3)) * 512 + (kt & 15) * 32;
#pragma unroll
        for (int rr = 0; rr < 2; ++rr)
            gload_lds16(pad + imoffB[rr] + shift, (u16*)(&Bs[s][0] + (wid * 2 + rr) * 512));
    };

    STAGE_CA(0, 0); STAGE_CB(0, 0);
    STAGE_CA(1, 1); STAGE_CB(1, 1);
    STAGE_CA(2, 2); STAGE_CB(2, 2);
    asm volatile("s_waitcnt vmcnt(6)" ::: "memory");
    __builtin_amdgcn_sched_barrier(0);
    __builtin_amdgcn_s_barrier();
    __builtin_amdgcn_sched_barrier(0);

    short8 A0[4], A1[4], B0[4], B1[4];
#pragma unroll
    for (int i = 0; i < 4; ++i) A0[i] = *(const short8*)(&As[0][0] + aoff + i * 512);
#pragma unroll
    for (int j = 0; j < 4; ++j) B0[j] = *(const short8*)(&Bs[0][0] + boff + j * 512);

#define CSTEP(KT, BUFR, BUFS, AM, BMF, AR, BRF)                                   \
    {                                                                             \
        if ((KT) >= 142) asm volatile("s_waitcnt vmcnt(0)" ::: "memory");         \
        else             asm volatile("s_waitcnt vmcnt(3)" ::: "memory");         \
        __builtin_amdgcn_sched_barrier(0);                                        \
        __builtin_amdgcn_s_barrier();                                             \
        __builtin_amdgcn_sched_barrier(0);                                        \
        if ((KT) < 143) {                                                         \
            const short* Abr = &As[BUFR][0];                                      \
            const short* Bbr = &Bs[BUFR][0];                                      \
            _Pragma("unroll")                                                     \
            for (int i = 0; i < 4; ++i) AR[i] = *(const short8*)(Abr + aoff + i * 512);  \
            _Pragma("unroll")                                                     \
            for (int j = 0; j < 4; ++j) BRF[j] = *(const short8*)(Bbr + boff + j * 512); \
        }                                                                         \
        if ((KT) + 3 < 144) { STAGE_CA((KT) + 3, BUFS); STAGE_CB((KT) + 3, BUFS); } \
        __builtin_amdgcn_s_setprio(1);                                            \
        _Pragma("unroll")                                                         \
        for (int i = 0; i < 4; ++i)                                               \
            _Pragma("unroll")                                                     \
            for (int j = 0; j < 4; ++j)                                           \
                acc[i][j] = __builtin_amdgcn_mfma_f32_16x16x32_bf16(AM[i], BMF[j], acc[i][j], 0, 0, 0); \
        __builtin_amdgcn_s_setprio(0);                                            \
    }

#pragma unroll 1
    for (int kt = 0; kt < 144; kt += 4) {
        CSTEP(kt + 0, 1, 3, A0, B0, A1, B1);
        CSTEP(kt + 1, 2, 0, A1, B1, A0, B0);
        CSTEP(kt + 2, 3, 1, A0, B0, A1, B1);
        CSTEP(kt + 3, 0, 2, A1, B1, A0, B0);
    }
#undef CSTEP

#pragma unroll
    for (int i = 0; i < 4; ++i)
#pragma unroll
        for (int j = 0; j < 4; ++j)
#pragma unroll
            for (int r = 0; r < 4; ++r) {
                int co = cobase + wm * 64 + i * 16 + (l >> 4) * 4 + r;
                int imrow = imbase + wn * 64 + j * 16 + (l & 15);
                int n = imrow >> 8, p = imrow & 255;
                size_t addr = (((size_t)(n * 512 + co)) << 8) + p;
                out[addr] = acc[i][j][r] + xres[addr];
            }
}

// ---------------------------------------------------------------------------
// attention per pixel (bf16 in, bf16 out in place of v) — unchanged
// ---------------------------------------------------------------------------
__global__ __launch_bounds__(256) void attn_kernel(
    const u16* __restrict__ qT, const u16* __restrict__ kT, u16* vvT)
{
    const int p = blockIdx.x;
    const int t = threadIdx.x;
    __shared__ float smemA[2][64][68];
    __shared__ float attb[64][68];
    const size_t pb = (size_t)p * (NB * CCH);

    const int ng = t >> 4, mg = t & 15;
    const int n0 = ng * 4, m0 = mg * 4;
    float acc[4][4];
#pragma unroll
    for (int i = 0; i < 4; ++i)
#pragma unroll
        for (int j = 0; j < 4; ++j) acc[i][j] = 0.f;

    for (int ct = 0; ct < 8; ++ct) {
        const int c0 = ct * 64;
        __syncthreads();
#pragma unroll
        for (int s = 0; s < 2; ++s) {
            int f = t + s * 256;
            int nn = f >> 3, c8 = (f & 7) * 8;
            short8 qv = *(const short8*)(qT + pb + (size_t)nn * CCH + c0 + c8);
            short8 kv = *(const short8*)(kT + pb + (size_t)nn * CCH + c0 + c8);
#pragma unroll
            for (int e = 0; e < 8; ++e) {
                smemA[0][nn][c8 + e] = bf2f((u16)qv[e]);
                smemA[1][nn][c8 + e] = bf2f((u16)kv[e]);
            }
        }
        __syncthreads();
#pragma unroll 4
        for (int c4 = 0; c4 < 16; ++c4) {
            float4 q4[4], k4[4];
#pragma unroll
            for (int i = 0; i < 4; ++i) q4[i] = *(const float4*)&smemA[0][n0 + i][c4 * 4];
#pragma unroll
            for (int j = 0; j < 4; ++j) k4[j] = *(const float4*)&smemA[1][m0 + j][c4 * 4];
#pragma unroll
            for (int i = 0; i < 4; ++i)
#pragma unroll
                for (int j = 0; j < 4; ++j) {
                    acc[i][j] = fmaf(q4[i].x, k4[j].x, acc[i][j]);
                    acc[i][j] = fmaf(q4[i].y, k4[j].y, acc[i][j]);
                    acc[i][j] = fmaf(q4[i].z, k4[j].z, acc[i][j]);
                    acc[i][j] = fmaf(q4[i].w, k4[j].w, acc[i][j]);
                }
        }
    }

    const float SCALE = 0.0441941738241592f;  // 1/sqrt(512)
#pragma unroll
    for (int i = 0; i < 4; ++i) {
        float m = fmaxf(fmaxf(acc[i][0], acc[i][1]), fmaxf(acc[i][2], acc[i][3]));
#pragma unroll
        for (int mask = 1; mask < 16; mask <<= 1) m = fmaxf(m, __shfl_xor(m, mask, 16));
        float e[4]; float s = 0.f;
#pragma unroll
        for (int j = 0; j < 4; ++j) { e[j] = __expf((acc[i][j] - m) * SCALE); s += e[j]; }
#pragma unroll
        for (int mask = 1; mask < 16; mask <<= 1) s += __shfl_xor(s, mask, 16);
        float inv = 1.f / s;
#pragma unroll
        for (int j = 0; j < 4; ++j) attb[n0 + i][m0 + j] = e[j] * inv;
    }
    __syncthreads();

    float* vs = &smemA[0][0][0];  // vs[m*132 + c]
    const int ng2 = t >> 3, cg = t & 7;
    const int nn0 = ng2 * 2, cb = cg * 16;
    for (int ct4 = 0; ct4 < 4; ++ct4) {
        const int c0 = ct4 * 128;
#pragma unroll
        for (int s = 0; s < 4; ++s) {
            int f = t + s * 256;
            int m = f >> 4, c8 = (f & 15) * 8;
            short8 vv = *(const short8*)(vvT + pb + (size_t)m * CCH + c0 + c8);
#pragma unroll
            for (int e = 0; e < 8; ++e) vs[m * 132 + c8 + e] = bf2f((u16)vv[e]);
        }
        __syncthreads();
        float acc2[2][16];
#pragma unroll
        for (int i = 0; i < 2; ++i)
#pragma unroll
            for (int j = 0; j < 16; ++j) acc2[i][j] = 0.f;
#pragma unroll 4
        for (int m = 0; m < 64; ++m) {
            float a0 = attb[nn0][m], a1 = attb[nn0 + 1][m];
#pragma unroll
            for (int k4 = 0; k4 < 4; ++k4) {
                float4 v4 = *(const float4*)&vs[m * 132 + cb + k4 * 4];
                acc2[0][k4 * 4 + 0] = fmaf(a0, v4.x, acc2[0][k4 * 4 + 0]);
                acc2[0][k4 * 4 + 1] = fmaf(a0, v4.y, acc2[0][k4 * 4 + 1]);
                acc2[0][k4 * 4 + 2] = fmaf(a0, v4.z, acc2[0][k4 * 4 + 2]);
                acc2[0][k4 * 4 + 3] = fmaf(a0, v4.w, acc2[0][k4 * 4 + 3]);
                acc2[1][k4 * 4 + 0] = fmaf(a1, v4.x, acc2[1][k4 * 4 + 0]);
                acc2[1][k4 * 4 + 1] = fmaf(a1, v4.y, acc2[1][k4 * 4 + 1]);
                acc2[1][k4 * 4 + 2] = fmaf(a1, v4.z, acc2[1][k4 * 4 + 2]);
                acc2[1][k4 * 4 + 3] = fmaf(a1, v4.w, acc2[1][k4 * 4 + 3]);
            }
        }
#pragma unroll
        for (int i = 0; i < 2; ++i)
#pragma unroll
            for (int j = 0; j < 16; ++j)
                vvT[pb + (size_t)(nn0 + i) * CCH + c0 + cb + j] = f2bf(acc2[i][j]);
        __syncthreads();
    }
}

// ---------------------------------------------------------------------------
// GroupNorm split: part1 = 256-block partial sums (deterministic, no atomics)
// ---------------------------------------------------------------------------
__global__ __launch_bounds__(256) void gn_part1(
    const u16* __restrict__ virtT, float* __restrict__ partials)
{
    const int n = blockIdx.x >> 2, qr = blockIdx.x & 3, t = threadIdx.x;
    float sum = 0.f, ss = 0.f;
#pragma unroll 4
    for (int it = 0; it < 16; ++it) {
        int f = t + it * 256;
        int p = qr * 64 + (f >> 6), c = (f & 63) * 8;
        short8 vv = *(const short8*)(virtT + ((size_t)(p * 64 + n)) * 512 + c);
#pragma unroll
        for (int e = 0; e < 8; ++e) { float x = bf2f((u16)vv[e]); sum += x; ss = fmaf(x, x, ss); }
    }
#pragma unroll
    for (int off = 32; off > 0; off >>= 1) {
        sum += __shfl_down(sum, off);
        ss  += __shfl_down(ss, off);
    }
    __shared__ float rs[4], rss[4];
    const int wid = t >> 6, lane = t & 63;
    if (lane == 0) { rs[wid] = sum; rss[wid] = ss; }
    __syncthreads();
    if (t == 0) {
        partials[(n * 4 + qr) * 2 + 0] = rs[0] + rs[1] + rs[2] + rs[3];
        partials[(n * 4 + qr) * 2 + 1] = rss[0] + rss[1] + rss[2] + rss[3];
    }
}

// part2: apply GN + affine + ReLU -> ypad bf16 [n][18][18][c]
__global__ __launch_bounds__(256) void gn_part2(
    const u16* __restrict__ virtT, const float* __restrict__ partials,
    const float* __restrict__ gamma, const float* __restrict__ beta,
    u16* __restrict__ ypad)
{
    const int n = blockIdx.x >> 2, qr = blockIdx.x & 3, t = threadIdx.x;
    __shared__ float sg[512], sb[512];
    for (int i = t; i < 512; i += 256) { sg[i] = gamma[i]; sb[i] = beta[i]; }
    float S = 0.f, SS = 0.f;
#pragma unroll
    for (int i = 0; i < 4; ++i) {
        S  += partials[(n * 4 + i) * 2 + 0];
        SS += partials[(n * 4 + i) * 2 + 1];
    }
    const float mu = S * (1.f / 131072.f);
    const float var = SS * (1.f / 131072.f) - mu * mu;
    const float rstd = rsqrtf(var + 1e-5f);
    __syncthreads();

#pragma unroll 4
    for (int it = 0; it < 16; ++it) {
        int f = t + it * 256;
        int p = qr * 64 + (f >> 6), cc = (f & 63) * 8;
        short8 vv = *(const short8*)(virtT + ((size_t)(p * 64 + n)) * 512 + cc);
        short8 ov;
#pragma unroll
        for (int e = 0; e < 8; ++e) {
            float x = (bf2f((u16)vv[e]) - mu) * rstd;
            x = fmaf(x, sg[cc + e], sb[cc + e]);
            ov[e] = (short)f2bf(fmaxf(x, 0.f));
        }
        int h = p >> 4, wcol = p & 15;
        *(short8*)(ypad + ((size_t)((n * 18 + h + 1) * 18 + wcol + 1)) * 512 + cc) = ov;
    }
}

// ---------------------------------------------------------------------------
extern "C" void kernel_launch(void* const* d_in, const int* in_sizes, int n_in,
                              void* d_out, int out_size, void* d_ws, size_t ws_size,
                              hipStream_t stream)
{
    const float* x     = (const float*)d_in[0];
    const float* Wq    = (const float*)d_in[1];
    const float* Wk    = (const float*)d_in[2];
    const float* Wv    = (const float*)d_in[3];
    const float* Wc    = (const float*)d_in[4];
    const float* gamma = (const float*)d_in[5];
    const float* beta  = (const float*)d_in[6];
    float* out = (float*)d_out;

    // workspace (u16 units): pad | Wt | q | k | v  (~90.4 MB total)
    u16* pad = (u16*)d_ws;
    u16* Wt  = pad + 10616832;
    u16* q   = Wt + 9437184;
    u16* k   = q + 8388608;
    u16* v   = k + 8388608;   // virt written in place after PV
    float* gnp = (float*)k;   // k is dead after attn; reuse for GN partials

    zero_borders<<<dim3(64), dim3(256), 0, stream>>>(pad);
    prep_x<<<dim3(4, 8, 64), dim3(256), 0, stream>>>(x, pad);
    prep_w<<<dim3(512, 4), dim3(256), 0, stream>>>(Wq, Wk, Wv, Wc, Wt);

    qkv_mfma8<<<dim3(512), dim3(512), 0, stream>>>(pad, Wt, q, k, v);
    attn_kernel<<<dim3(256), dim3(256), 0, stream>>>(q, k, v);
    gn_part1<<<dim3(256), dim3(256), 0, stream>>>(v, gnp);
    gn_part2<<<dim3(256), dim3(256), 0, stream>>>(v, gnp, gamma, beta, pad);
    cres_pipe<<<dim3(256), dim3(512), 0, stream>>>(pad, Wt + 3 * 2359296, x, out);
}